// Round 1
// 369.164 us; speedup vs baseline: 1.0365x; 1.0365x over previous
//
#include <hip/hip_runtime.h>
#include <math.h>

#define NUM_USERS 100000
#define NUM_ITEMS 50000
#define N_NODES   150000   // NUM_USERS + NUM_ITEMS
#define LATENT    64
#define N_EDGES   2400000
#define BATCH     16384

// Multisplit fill: 4096-edge chunks, 512-row buckets
#define CHUNK 4096
#define NBLK  ((N_EDGES + CHUNK - 1) / CHUNK)   // 586
#define NBKT  ((N_NODES + 511) / 512)           // 293

// bf16 helpers (values small/finite; RNE)
__device__ __forceinline__ unsigned short f2bf(float f) {
    unsigned u = __float_as_uint(f);
    u = (u + 0x7FFF + ((u >> 16) & 1)) >> 16;
    return (unsigned short)u;
}
__device__ __forceinline__ float bf2f(unsigned short h) {
    return __uint_as_float(((unsigned)h) << 16);
}

// ---------------------------------------------------------------------------
// table = bf16(concat(user_emb, item_emb))
// ---------------------------------------------------------------------------
__global__ void k_concat_bf16(const float4* __restrict__ ue,
                              const float4* __restrict__ ie,
                              ushort4* __restrict__ cur) {
    int i = blockIdx.x * blockDim.x + threadIdx.x;
    const int nU4 = NUM_USERS * (LATENT / 4);
    const int nT4 = N_NODES   * (LATENT / 4);
    if (i >= nT4) return;
    float4 v = (i < nU4) ? ue[i] : ie[i - nU4];
    ushort4 o;
    o.x = f2bf(v.x); o.y = f2bf(v.y); o.z = f2bf(v.z); o.w = f2bf(v.w);
    cur[i] = o;
}

// ---------------------------------------------------------------------------
// vsel[b, 0:64] = user_emb[users[b]] ; vsel[b,64:128] = item_emb[items[b]]
// ---------------------------------------------------------------------------
__global__ void k_sel_init(const int* __restrict__ users,
                           const int* __restrict__ items,
                           const float* __restrict__ ue,
                           const float* __restrict__ ie,
                           float* __restrict__ vsel) {
    int t = blockIdx.x * blockDim.x + threadIdx.x;
    int b = t >> 6, d = t & 63;
    vsel[b * 128 + d]      = ue[users[b] * 64 + d];
    vsel[b * 128 + 64 + d] = ie[items[b] * 64 + d];
}

// ---------------------------------------------------------------------------
// Multisplit p1a: per-block bucket histogram -> cmat[bucket][block]
// ---------------------------------------------------------------------------
__global__ __launch_bounds__(256) void k_p1a(const int* __restrict__ rows,
                                             int* __restrict__ cmat) {
    __shared__ int hist[NBKT];
    for (int i = threadIdx.x; i < NBKT; i += 256) hist[i] = 0;
    __syncthreads();
    int e0 = blockIdx.x * CHUNK;
    int cnt = min(CHUNK, N_EDGES - e0);
    for (int t = threadIdx.x; t < cnt; t += 256)
        atomicAdd(&hist[rows[e0 + t] >> 9], 1);
    __syncthreads();
    for (int i = threadIdx.x; i < NBKT; i += 256)
        cmat[i * NBLK + blockIdx.x] = hist[i];
}

// ---------------------------------------------------------------------------
// Multisplit p1b: per-bucket exclusive scan over blocks; emit bucket total.
// ---------------------------------------------------------------------------
__global__ __launch_bounds__(1024) void k_p1b(int* __restrict__ cmat,
                                              int* __restrict__ btotal) {
    __shared__ int sh[1024];
    int k = blockIdx.x;
    int v = (threadIdx.x < NBLK) ? cmat[k * NBLK + threadIdx.x] : 0;
    sh[threadIdx.x] = v;
    __syncthreads();
    for (int off = 1; off < 1024; off <<= 1) {
        int t = (threadIdx.x >= off) ? sh[threadIdx.x - off] : 0;
        __syncthreads();
        sh[threadIdx.x] += t;
        __syncthreads();
    }
    if (threadIdx.x < NBLK)
        cmat[k * NBLK + threadIdx.x] = sh[threadIdx.x] - v;   // exclusive
    if (threadIdx.x == 1023) btotal[k] = sh[1023];
}

// ---------------------------------------------------------------------------
// Bucket-base scan: exclusive scan of 293 bucket totals -> bbase[0..NBKT]
// ---------------------------------------------------------------------------
__global__ __launch_bounds__(512) void k_bscan(const int* __restrict__ btotal,
                                               int* __restrict__ bbase) {
    __shared__ int sh[512];
    int v = (threadIdx.x < NBKT) ? btotal[threadIdx.x] : 0;
    sh[threadIdx.x] = v;
    __syncthreads();
    for (int off = 1; off < 512; off <<= 1) {
        int t = (threadIdx.x >= off) ? sh[threadIdx.x - off] : 0;
        __syncthreads();
        sh[threadIdx.x] += t;
        __syncthreads();
    }
    if (threadIdx.x < NBKT) bbase[threadIdx.x] = sh[threadIdx.x] - v;
    if (threadIdx.x == NBKT) bbase[NBKT] = N_EDGES;
}

// ---------------------------------------------------------------------------
// Multisplit p1c: re-read chunk, bin records in LDS, flush bucket-contiguous
// runs at exact offsets (cmat + bbase). Zero global atomics.
// Record: x = col(18b) | rowLo(9b)<<18 ; y = fp32 val bits.
// ---------------------------------------------------------------------------
__global__ __launch_bounds__(256) void k_p1c(const int* __restrict__ rows,
                                             const int* __restrict__ cols,
                                             const float* __restrict__ vals,
                                             const int* __restrict__ offs,
                                             const int* __restrict__ bbase,
                                             int2* __restrict__ staged) {
    __shared__ int hist[NBKT];
    __shared__ int lstart[NBKT];
    __shared__ int cursor[NBKT];
    __shared__ int soffs[NBKT];
    __shared__ int sc[512];
    __shared__ int2 st[CHUNK];
    __shared__ unsigned short bkt16[CHUNK];

    int e0 = blockIdx.x * CHUNK;
    int cnt = min(CHUNK, N_EDGES - e0);
    for (int i = threadIdx.x; i < NBKT; i += 256) {
        hist[i] = 0; cursor[i] = 0;
        soffs[i] = offs[i * NBLK + blockIdx.x] + bbase[i];
    }
    sc[threadIdx.x] = 0; sc[threadIdx.x + 256] = 0;
    __syncthreads();
    for (int t = threadIdx.x; t < cnt; t += 256)
        atomicAdd(&hist[rows[e0 + t] >> 9], 1);
    __syncthreads();
    for (int i = threadIdx.x; i < NBKT; i += 256) sc[i] = hist[i];
    __syncthreads();
    // inclusive scan over 512 slots (256 threads x 2, Hillis-Steele)
    for (int off = 1; off < 512; off <<= 1) {
        int a0 = (threadIdx.x >= off)       ? sc[threadIdx.x - off]       : 0;
        int a1 = (threadIdx.x + 256 >= off) ? sc[threadIdx.x + 256 - off] : 0;
        __syncthreads();
        sc[threadIdx.x]       += a0;
        sc[threadIdx.x + 256] += a1;
        __syncthreads();
    }
    for (int i = threadIdx.x; i < NBKT; i += 256) lstart[i] = sc[i] - hist[i];
    __syncthreads();
    // bin into LDS staging
    for (int t = threadIdx.x; t < cnt; t += 256) {
        int r = rows[e0 + t];
        int b = r >> 9;
        int p = lstart[b] + atomicAdd(&cursor[b], 1);
        st[p] = make_int2(cols[e0 + t] | ((r & 511) << 18),
                          __float_as_int(vals[e0 + t]));
        bkt16[p] = (unsigned short)b;
    }
    __syncthreads();
    // flush: consecutive threads in a bucket write consecutive global addrs
    for (int t = threadIdx.x; t < cnt; t += 256) {
        int b = bkt16[t];
        staged[soffs[b] + (t - lstart[b])] = st[t];
    }
}

// ---------------------------------------------------------------------------
// Multisplit p2: one block per bucket; row histogram from staged records,
// LDS scan -> local row starts, place records, emit counts/startArr.
// ---------------------------------------------------------------------------
__global__ __launch_bounds__(256) void k_p2(const int* __restrict__ bbase,
                                            const int2* __restrict__ staged,
                                            int2* __restrict__ edges,
                                            int* __restrict__ counts,
                                            int* __restrict__ startArr) {
    __shared__ int hist[512];
    __shared__ int lstart[512];
    __shared__ int cur[512];
    __shared__ int sc[512];
    int k = blockIdx.x;
    int rowBase = k << 9;
    int numRows = min(512, N_NODES - rowBase);
    int base = bbase[k];
    int end  = bbase[k + 1];
    hist[threadIdx.x] = 0;       hist[threadIdx.x + 256] = 0;
    cur[threadIdx.x] = 0;        cur[threadIdx.x + 256] = 0;
    __syncthreads();
    int cnt = end - base;
    for (int t = threadIdx.x; t < cnt; t += 256)
        atomicAdd(&hist[((unsigned)staged[base + t].x) >> 18], 1);
    __syncthreads();
    sc[threadIdx.x] = hist[threadIdx.x];
    sc[threadIdx.x + 256] = hist[threadIdx.x + 256];
    __syncthreads();
    for (int off = 1; off < 512; off <<= 1) {
        int a0 = (threadIdx.x >= off)       ? sc[threadIdx.x - off]       : 0;
        int a1 = (threadIdx.x + 256 >= off) ? sc[threadIdx.x + 256 - off] : 0;
        __syncthreads();
        sc[threadIdx.x]       += a0;
        sc[threadIdx.x + 256] += a1;
        __syncthreads();
    }
    lstart[threadIdx.x]       = sc[threadIdx.x]       - hist[threadIdx.x];
    lstart[threadIdx.x + 256] = sc[threadIdx.x + 256] - hist[threadIdx.x + 256];
    __syncthreads();
    for (int t = threadIdx.x; t < cnt; t += 256) {
        int2 rec = staged[base + t];
        int rl = ((unsigned)rec.x) >> 18;
        int c  = rec.x & 0x3FFFF;
        int off = lstart[rl] + atomicAdd(&cur[rl], 1);
        edges[base + off] = make_int2(c, rec.y);
    }
    for (int i = threadIdx.x; i < numRows; i += 256) {
        counts[rowBase + i]   = hist[i];
        startArr[rowBase + i] = base + lstart[i];
    }
}

// ---------------------------------------------------------------------------
// Pair-gather SpMM core.
// Wave split into two 32-lane halves: lanes 0-31 process EVEN edges, lanes
// 32-63 ODD edges. Each lane reads one uint (2 packed bf16 dims) so a half
// covers the full 128 B row -> ONE vmem instruction fetches TWO edges' rows.
// Flight of 8 pairs = 16 edges in flight before the first fma (one latency
// flight covers the average row, n_avg = 16). Exact tails of 4/2/1 pairs,
// then an odd-edge step where the upper half contributes v = 0.
// acc0/acc1 hold dims (2l, 2l+1) partial sums; caller combines halves via
// __shfl_xor(,32).
// ---------------------------------------------------------------------------
template<int P>
__device__ __forceinline__ void flight(const int2* __restrict__ edges,
                                       const unsigned* __restrict__ tab32,
                                       int s, int q, int half, int l,
                                       float& acc0, float& acc1) {
    unsigned w[P];
    float    v[P];
    #pragma unroll
    for (int t = 0; t < P; t++) {
        int2 eA = edges[s + 2 * (q + t)];       // uniform addr -> s_load
        int2 eB = edges[s + 2 * (q + t) + 1];
        int   c = half ? eB.x : eA.x;
        v[t] = __int_as_float(half ? eB.y : eA.y);
        w[t] = tab32[(size_t)c * 32 + l];       // 32 lanes x 4B = full row
    }
    #pragma unroll
    for (int t = 0; t < P; t++) {
        acc0 = fmaf(v[t], __uint_as_float(w[t] << 16),          acc0);
        acc1 = fmaf(v[t], __uint_as_float(w[t] & 0xffff0000u),  acc1);
    }
}

__device__ __forceinline__ void spmm_row(const int2* __restrict__ edges,
                                         const unsigned* __restrict__ tab32,
                                         int s, int n, int half, int l,
                                         float& acc0, float& acc1) {
    int npair = n >> 1;
    int q = 0;
    for (; q + 8 <= npair; q += 8)
        flight<8>(edges, tab32, s, q, half, l, acc0, acc1);
    if (npair - q >= 4) { flight<4>(edges, tab32, s, q, half, l, acc0, acc1); q += 4; }
    if (npair - q >= 2) { flight<2>(edges, tab32, s, q, half, l, acc0, acc1); q += 2; }
    if (npair - q >= 1) { flight<1>(edges, tab32, s, q, half, l, acc0, acc1); q += 1; }
    if (n & 1) {                                 // last (odd) edge
        int2 e = edges[s + n - 1];
        float v = half ? 0.f : __int_as_float(e.y);   // upper half: no-op
        unsigned w = tab32[(size_t)e.x * 32 + l];
        acc0 = fmaf(v, __uint_as_float(w << 16),         acc0);
        acc1 = fmaf(v, __uint_as_float(w & 0xffff0000u), acc1);
    }
}

// ---------------------------------------------------------------------------
// Gather SpMM (bf16): one wave per row, pair-gather layout.
// ---------------------------------------------------------------------------
__global__ __launch_bounds__(256) void k_spmm_csr(const int* __restrict__ startArr,
                                                  const int* __restrict__ counts,
                                                  const int2* __restrict__ edges,
                                                  const unsigned short* __restrict__ cur,
                                                  unsigned short* __restrict__ nxt) {
    int row  = blockIdx.x * 4 + (threadIdx.x >> 6);
    if (row >= N_NODES) return;
    row = __builtin_amdgcn_readfirstlane(row);
    int lane = threadIdx.x & 63;
    int half = lane >> 5;
    int l    = lane & 31;
    int s = __builtin_amdgcn_readfirstlane(startArr[row]);
    int n = __builtin_amdgcn_readfirstlane(counts[row]);
    const unsigned* tab32 = (const unsigned*)cur;

    float acc0 = 0.f, acc1 = 0.f;
    spmm_row(edges, tab32, s, n, half, l, acc0, acc1);

    // combine even/odd halves
    acc0 += __shfl_xor(acc0, 32);
    acc1 += __shfl_xor(acc1, 32);
    if (half == 0) {
        unsigned out = (unsigned)f2bf(acc0) | ((unsigned)f2bf(acc1) << 16);
        ((unsigned*)nxt)[(size_t)row * 32 + l] = out;
    }
}

// ---------------------------------------------------------------------------
// Fused layer-3 + layer-2 gather_add at selected rows (pair-gather layout).
// ---------------------------------------------------------------------------
__global__ __launch_bounds__(256) void k_spmm_sel(const int* __restrict__ users,
                                                  const int* __restrict__ items,
                                                  const int* __restrict__ startArr,
                                                  const int* __restrict__ counts,
                                                  const int2* __restrict__ edges,
                                                  const unsigned short* __restrict__ cur,
                                                  float* __restrict__ vsel) {
    int wave = blockIdx.x * 4 + (threadIdx.x >> 6);
    int lane = threadIdx.x & 63;
    int half = lane >> 5;
    int l    = lane & 31;
    int b, row, off;
    if (wave < BATCH) { b = wave;         row = users[b];             off = 0; }
    else              { b = wave - BATCH; row = NUM_USERS + items[b]; off = 64; }
    row = __builtin_amdgcn_readfirstlane(row);
    int s = __builtin_amdgcn_readfirstlane(startArr[row]);
    int n = __builtin_amdgcn_readfirstlane(counts[row]);
    const unsigned* tab32 = (const unsigned*)cur;

    float acc0 = 0.f, acc1 = 0.f;
    if (half == 0) {                       // layer-2 contribution (once)
        unsigned w = tab32[(size_t)row * 32 + l];
        acc0 = __uint_as_float(w << 16);
        acc1 = __uint_as_float(w & 0xffff0000u);
    }
    spmm_row(edges, tab32, s, n, half, l, acc0, acc1);

    acc0 += __shfl_xor(acc0, 32);
    acc1 += __shfl_xor(acc1, 32);
    if (half == 0) {
        float2* p = (float2*)(vsel + (size_t)b * 128 + off);
        float2 t = p[l];
        t.x += acc0; t.y += acc1;
        p[l] = t;
    }
}

// ---------------------------------------------------------------------------
// vsel += bf16 src at selected rows (after layer 1)
// ---------------------------------------------------------------------------
__global__ void k_gather_add(const int* __restrict__ users,
                             const int* __restrict__ items,
                             const unsigned short* __restrict__ src,
                             float* __restrict__ vsel) {
    int t = blockIdx.x * blockDim.x + threadIdx.x;
    int b = t >> 6, d = t & 63;
    vsel[b * 128 + d]      += bf2f(src[(size_t)users[b] * 64 + d]);
    vsel[b * 128 + 64 + d] += bf2f(src[(size_t)(NUM_USERS + items[b]) * 64 + d]);
}

// ---------------------------------------------------------------------------
// MLP head v2: one THREAD per batch row, no cross-lane ops.
// ---------------------------------------------------------------------------
__global__ __launch_bounds__(256) void k_mlp(const float* __restrict__ vsel,
                                             const float* __restrict__ W0,
                                             const float* __restrict__ b0,
                                             const float* __restrict__ W1,
                                             const float* __restrict__ b1,
                                             const float* __restrict__ Wa,
                                             const float* __restrict__ ba,
                                             float* __restrict__ out) {
    __shared__ float sW0[128 * 64];
    __shared__ float sW1[64 * 32];
    __shared__ float sWa[32];
    __shared__ float sb0[64];
    __shared__ float sb1[32];

    for (int i = threadIdx.x; i < 128 * 64; i += 256) sW0[i] = W0[i];
    for (int i = threadIdx.x; i < 64 * 32;  i += 256) sW1[i] = W1[i];
    if (threadIdx.x < 32) sWa[threadIdx.x] = Wa[threadIdx.x];
    if (threadIdx.x < 64) sb0[threadIdx.x] = b0[threadIdx.x];
    if (threadIdx.x >= 64 && threadIdx.x < 96) sb1[threadIdx.x - 64] = b1[threadIdx.x - 64];
    float sba = ba[0];
    __syncthreads();

    int b = blockIdx.x * 256 + threadIdx.x;          // one row per thread
    const float4* v4 = (const float4*)(vsel + (size_t)b * 128);

    float h0[64];
    #pragma unroll
    for (int j = 0; j < 64; j++) h0[j] = sb0[j];

    for (int k0 = 0; k0 < 32; k0++) {                // 32 float4 = 128 inputs
        float4 va = v4[k0];
        float a0 = va.x * 0.25f, a1 = va.y * 0.25f;
        float a2 = va.z * 0.25f, a3 = va.w * 0.25f;
        const float* w = &sW0[(k0 * 4) * 64];
        #pragma unroll
        for (int j = 0; j < 64; j++) {
            h0[j] = fmaf(a0, w[j],       h0[j]);
            h0[j] = fmaf(a1, w[64 + j],  h0[j]);
            h0[j] = fmaf(a2, w[128 + j], h0[j]);
            h0[j] = fmaf(a3, w[192 + j], h0[j]);
        }
    }
    #pragma unroll
    for (int j = 0; j < 64; j++) h0[j] = fmaxf(h0[j], 0.f);

    float h1[32];
    #pragma unroll
    for (int j = 0; j < 32; j++) h1[j] = sb1[j];
    for (int k = 0; k < 64; k++) {
        float a = h0[k];
        const float* w = &sW1[k * 32];
        #pragma unroll
        for (int j = 0; j < 32; j++)
            h1[j] = fmaf(a, w[j], h1[j]);
    }

    float logit = sba;
    #pragma unroll
    for (int j = 0; j < 32; j++)
        logit = fmaf(fmaxf(h1[j], 0.f), sWa[j], logit);

    out[b] = 1.0f / (1.0f + expf(-logit));
}

// ---------------------------------------------------------------------------
extern "C" void kernel_launch(void* const* d_in, const int* in_sizes, int n_in,
                              void* d_out, int out_size, void* d_ws, size_t ws_size,
                              hipStream_t stream) {
    const int*   users = (const int*)  d_in[0];
    const int*   items = (const int*)  d_in[1];
    const int*   rows  = (const int*)  d_in[2];
    const int*   cols  = (const int*)  d_in[3];
    const float* vals  = (const float*)d_in[4];
    const float* ue    = (const float*)d_in[5];
    const float* ie    = (const float*)d_in[6];
    const float* W0    = (const float*)d_in[7];
    const float* b0    = (const float*)d_in[8];
    const float* W1    = (const float*)d_in[9];
    const float* b1    = (const float*)d_in[10];
    const float* Wa    = (const float*)d_in[11];
    const float* ba    = (const float*)d_in[12];
    float* out = (float*)d_out;

    const size_t nodeElems = (size_t)N_NODES * LATENT;   // 9.6 M
    char* ws = (char*)d_ws;
    unsigned short* tabA = (unsigned short*)ws;  ws += nodeElems * 2;            // 19.2 MB
    unsigned short* tabB = (unsigned short*)ws;  ws += nodeElems * 2;            // 19.2 MB
    float* vsel = (float*)ws;                    ws += (size_t)BATCH * 128 * 4;  // 8.39 MB
    int2*  edges  = (int2*)ws;                   ws += (size_t)N_EDGES * 8;      // 19.2 MB
    int2*  staged = (int2*)ws;                   ws += (size_t)N_EDGES * 8;      // 19.2 MB
    int* counts   = (int*)ws;                    ws += N_NODES * 4;
    int* startArr = (int*)ws;                    ws += N_NODES * 4;
    int* cmat     = (int*)ws;                    ws += (size_t)NBKT * NBLK * 4;  // 686 KB
    int* btotal   = (int*)ws;                    ws += NBKT * 4;
    int* bbase    = (int*)ws;                    ws += (NBKT + 1) * 4;

    const int gGrid = (BATCH * 64) / 256;

    // bf16 table + fp32 layer-0 selection
    k_concat_bf16<<<(N_NODES * (LATENT / 4) + 255) / 256, 256, 0, stream>>>(
        (const float4*)ue, (const float4*)ie, (ushort4*)tabA);
    k_sel_init<<<gGrid, 256, 0, stream>>>(users, items, ue, ie, vsel);

    // ---- CSR build: zero global atomics, no row histogram ----
    k_p1a<<<NBLK, 256, 0, stream>>>(rows, cmat);
    k_p1b<<<NBKT, 1024, 0, stream>>>(cmat, btotal);
    k_bscan<<<1, 512, 0, stream>>>(btotal, bbase);
    k_p1c<<<NBLK, 256, 0, stream>>>(rows, cols, vals, cmat, bbase, staged);
    k_p2<<<NBKT, 256, 0, stream>>>(bbase, staged, edges, counts, startArr);

    // layer 1: A -> B (writes every row; no memset needed)
    k_spmm_csr<<<(N_NODES + 3) / 4, 256, 0, stream>>>(startArr, counts, edges, tabA, tabB);
    k_gather_add<<<gGrid, 256, 0, stream>>>(users, items, tabB, vsel);

    // layer 2: B -> A
    k_spmm_csr<<<(N_NODES + 3) / 4, 256, 0, stream>>>(startArr, counts, edges, tabB, tabA);

    // layer 3 (selected rows only) fused with layer-2 gather_add
    k_spmm_sel<<<(2 * BATCH) / 4, 256, 0, stream>>>(users, items, startArr,
                                                    counts, edges, tabA, vsel);

    // MLP head: one thread per row
    k_mlp<<<BATCH / 256, 256, 0, stream>>>(vsel, W0, b0, W1, b1, Wa, ba, out);
}

// Round 2
// 366.735 us; speedup vs baseline: 1.0434x; 1.0066x over previous
//
#include <hip/hip_runtime.h>
#include <math.h>

#define NUM_USERS 100000
#define NUM_ITEMS 50000
#define N_NODES   150000   // NUM_USERS + NUM_ITEMS
#define LATENT    64
#define N_EDGES   2400000
#define BATCH     16384

// Multisplit fill: 4096-edge chunks, 512-row buckets
#define CHUNK 4096
#define NBLK  ((N_EDGES + CHUNK - 1) / CHUNK)   // 586
#define NBKT  ((N_NODES + 511) / 512)           // 293

typedef __attribute__((ext_vector_type(2))) float floatx2;

// fp8 e4m3 pack/unpack via gfx950 HW converters (encode+decode self-consistent)
__device__ __forceinline__ unsigned pk4_fp8(float a, float b, float c, float d) {
    int u = __builtin_amdgcn_cvt_pk_fp8_f32(a, b, 0, false);
    u     = __builtin_amdgcn_cvt_pk_fp8_f32(c, d, u, true);
    return (unsigned)u;
}

// ---------------------------------------------------------------------------
// table = fp8(concat(user_emb, item_emb)) ; 16 uints per node row
// ---------------------------------------------------------------------------
__global__ void k_concat_fp8(const float4* __restrict__ ue,
                             const float4* __restrict__ ie,
                             unsigned* __restrict__ cur) {
    int i = blockIdx.x * blockDim.x + threadIdx.x;
    const int nU4 = NUM_USERS * 16;
    const int nT4 = N_NODES   * 16;
    if (i >= nT4) return;
    float4 v = (i < nU4) ? ue[i] : ie[i - nU4];
    cur[i] = pk4_fp8(v.x, v.y, v.z, v.w);
}

// ---------------------------------------------------------------------------
// vsel[b, 0:64] = user_emb[users[b]] ; vsel[b,64:128] = item_emb[items[b]]
// ---------------------------------------------------------------------------
__global__ void k_sel_init(const int* __restrict__ users,
                           const int* __restrict__ items,
                           const float* __restrict__ ue,
                           const float* __restrict__ ie,
                           float* __restrict__ vsel) {
    int t = blockIdx.x * blockDim.x + threadIdx.x;
    int b = t >> 6, d = t & 63;
    vsel[b * 128 + d]      = ue[users[b] * 64 + d];
    vsel[b * 128 + 64 + d] = ie[items[b] * 64 + d];
}

// ---------------------------------------------------------------------------
// Multisplit p1a: per-block bucket histogram -> cmat[bucket][block]
// ---------------------------------------------------------------------------
__global__ __launch_bounds__(256) void k_p1a(const int* __restrict__ rows,
                                             int* __restrict__ cmat) {
    __shared__ int hist[NBKT];
    for (int i = threadIdx.x; i < NBKT; i += 256) hist[i] = 0;
    __syncthreads();
    int e0 = blockIdx.x * CHUNK;
    int cnt = min(CHUNK, N_EDGES - e0);
    for (int t = threadIdx.x; t < cnt; t += 256)
        atomicAdd(&hist[rows[e0 + t] >> 9], 1);
    __syncthreads();
    for (int i = threadIdx.x; i < NBKT; i += 256)
        cmat[i * NBLK + blockIdx.x] = hist[i];
}

// ---------------------------------------------------------------------------
// Multisplit p1b: per-bucket exclusive scan over blocks; emit bucket total.
// ---------------------------------------------------------------------------
__global__ __launch_bounds__(1024) void k_p1b(int* __restrict__ cmat,
                                              int* __restrict__ btotal) {
    __shared__ int sh[1024];
    int k = blockIdx.x;
    int v = (threadIdx.x < NBLK) ? cmat[k * NBLK + threadIdx.x] : 0;
    sh[threadIdx.x] = v;
    __syncthreads();
    for (int off = 1; off < 1024; off <<= 1) {
        int t = (threadIdx.x >= off) ? sh[threadIdx.x - off] : 0;
        __syncthreads();
        sh[threadIdx.x] += t;
        __syncthreads();
    }
    if (threadIdx.x < NBLK)
        cmat[k * NBLK + threadIdx.x] = sh[threadIdx.x] - v;   // exclusive
    if (threadIdx.x == 1023) btotal[k] = sh[1023];
}

// ---------------------------------------------------------------------------
// Bucket-base scan: exclusive scan of 293 bucket totals -> bbase[0..NBKT]
// ---------------------------------------------------------------------------
__global__ __launch_bounds__(512) void k_bscan(const int* __restrict__ btotal,
                                               int* __restrict__ bbase) {
    __shared__ int sh[512];
    int v = (threadIdx.x < NBKT) ? btotal[threadIdx.x] : 0;
    sh[threadIdx.x] = v;
    __syncthreads();
    for (int off = 1; off < 512; off <<= 1) {
        int t = (threadIdx.x >= off) ? sh[threadIdx.x - off] : 0;
        __syncthreads();
        sh[threadIdx.x] += t;
        __syncthreads();
    }
    if (threadIdx.x < NBKT) bbase[threadIdx.x] = sh[threadIdx.x] - v;
    if (threadIdx.x == NBKT) bbase[NBKT] = N_EDGES;
}

// ---------------------------------------------------------------------------
// Multisplit p1c: re-read chunk, bin records in LDS, flush bucket-contiguous
// runs at exact offsets (cmat + bbase). Zero global atomics.
// Record: x = col(18b) | rowLo(9b)<<18 ; y = fp32 val bits.
// ---------------------------------------------------------------------------
__global__ __launch_bounds__(256) void k_p1c(const int* __restrict__ rows,
                                             const int* __restrict__ cols,
                                             const float* __restrict__ vals,
                                             const int* __restrict__ offs,
                                             const int* __restrict__ bbase,
                                             int2* __restrict__ staged) {
    __shared__ int hist[NBKT];
    __shared__ int lstart[NBKT];
    __shared__ int cursor[NBKT];
    __shared__ int soffs[NBKT];
    __shared__ int sc[512];
    __shared__ int2 st[CHUNK];
    __shared__ unsigned short bkt16[CHUNK];

    int e0 = blockIdx.x * CHUNK;
    int cnt = min(CHUNK, N_EDGES - e0);
    for (int i = threadIdx.x; i < NBKT; i += 256) {
        hist[i] = 0; cursor[i] = 0;
        soffs[i] = offs[i * NBLK + blockIdx.x] + bbase[i];
    }
    sc[threadIdx.x] = 0; sc[threadIdx.x + 256] = 0;
    __syncthreads();
    for (int t = threadIdx.x; t < cnt; t += 256)
        atomicAdd(&hist[rows[e0 + t] >> 9], 1);
    __syncthreads();
    for (int i = threadIdx.x; i < NBKT; i += 256) sc[i] = hist[i];
    __syncthreads();
    // inclusive scan over 512 slots (256 threads x 2, Hillis-Steele)
    for (int off = 1; off < 512; off <<= 1) {
        int a0 = (threadIdx.x >= off)       ? sc[threadIdx.x - off]       : 0;
        int a1 = (threadIdx.x + 256 >= off) ? sc[threadIdx.x + 256 - off] : 0;
        __syncthreads();
        sc[threadIdx.x]       += a0;
        sc[threadIdx.x + 256] += a1;
        __syncthreads();
    }
    for (int i = threadIdx.x; i < NBKT; i += 256) lstart[i] = sc[i] - hist[i];
    __syncthreads();
    // bin into LDS staging
    for (int t = threadIdx.x; t < cnt; t += 256) {
        int r = rows[e0 + t];
        int b = r >> 9;
        int p = lstart[b] + atomicAdd(&cursor[b], 1);
        st[p] = make_int2(cols[e0 + t] | ((r & 511) << 18),
                          __float_as_int(vals[e0 + t]));
        bkt16[p] = (unsigned short)b;
    }
    __syncthreads();
    // flush: consecutive threads in a bucket write consecutive global addrs
    for (int t = threadIdx.x; t < cnt; t += 256) {
        int b = bkt16[t];
        staged[soffs[b] + (t - lstart[b])] = st[t];
    }
}

// ---------------------------------------------------------------------------
// Multisplit p2: one block per bucket; row histogram from staged records,
// LDS scan -> local row starts, place records, emit counts/startArr.
// ---------------------------------------------------------------------------
__global__ __launch_bounds__(256) void k_p2(const int* __restrict__ bbase,
                                            const int2* __restrict__ staged,
                                            int2* __restrict__ edges,
                                            int* __restrict__ counts,
                                            int* __restrict__ startArr) {
    __shared__ int hist[512];
    __shared__ int lstart[512];
    __shared__ int cur[512];
    __shared__ int sc[512];
    int k = blockIdx.x;
    int rowBase = k << 9;
    int numRows = min(512, N_NODES - rowBase);
    int base = bbase[k];
    int end  = bbase[k + 1];
    hist[threadIdx.x] = 0;       hist[threadIdx.x + 256] = 0;
    cur[threadIdx.x] = 0;        cur[threadIdx.x + 256] = 0;
    __syncthreads();
    int cnt = end - base;
    for (int t = threadIdx.x; t < cnt; t += 256)
        atomicAdd(&hist[((unsigned)staged[base + t].x) >> 18], 1);
    __syncthreads();
    sc[threadIdx.x] = hist[threadIdx.x];
    sc[threadIdx.x + 256] = hist[threadIdx.x + 256];
    __syncthreads();
    for (int off = 1; off < 512; off <<= 1) {
        int a0 = (threadIdx.x >= off)       ? sc[threadIdx.x - off]       : 0;
        int a1 = (threadIdx.x + 256 >= off) ? sc[threadIdx.x + 256 - off] : 0;
        __syncthreads();
        sc[threadIdx.x]       += a0;
        sc[threadIdx.x + 256] += a1;
        __syncthreads();
    }
    lstart[threadIdx.x]       = sc[threadIdx.x]       - hist[threadIdx.x];
    lstart[threadIdx.x + 256] = sc[threadIdx.x + 256] - hist[threadIdx.x + 256];
    __syncthreads();
    for (int t = threadIdx.x; t < cnt; t += 256) {
        int2 rec = staged[base + t];
        int rl = ((unsigned)rec.x) >> 18;
        int c  = rec.x & 0x3FFFF;
        int off = lstart[rl] + atomicAdd(&cur[rl], 1);
        edges[base + off] = make_int2(c, rec.y);
    }
    for (int i = threadIdx.x; i < numRows; i += 256) {
        counts[rowBase + i]   = hist[i];
        startArr[rowBase + i] = base + lstart[i];
    }
}

// ---------------------------------------------------------------------------
// Quad-gather SpMM core (fp8 table).
// 64 lanes = 4 groups of 16; group g handles edges 4q+g. Lane li in a group
// reads one uint (4 fp8 dims) -> 16 lanes cover the 64 B row. ONE vmem
// instruction fetches FOUR edges' rows (4 cache lines). Each lane keeps 4
// dim-accumulators (dims 4*li..4*li+3); groups combined by 2 shfl_xor.
// ---------------------------------------------------------------------------
template<int P>
__device__ __forceinline__ void qflight(const int2* __restrict__ edges,
                                        const unsigned* __restrict__ tab,
                                        int s, int q, int g, int li,
                                        float& a0, float& a1, float& a2, float& a3) {
    unsigned u[P];
    float    v[P];
    #pragma unroll
    for (int t = 0; t < P; t++) {
        int2 e = edges[s + 4 * (q + t) + g];   // 16 lanes share addr -> 1 line
        v[t] = __int_as_float(e.y);
        u[t] = tab[(size_t)e.x * 16 + li];     // 16 lanes x 4B = full 64B row
    }
    #pragma unroll
    for (int t = 0; t < P; t++) {
        floatx2 lo = __builtin_amdgcn_cvt_pk_f32_fp8(u[t], false);
        floatx2 hi = __builtin_amdgcn_cvt_pk_f32_fp8(u[t], true);
        a0 = fmaf(v[t], lo.x, a0);
        a1 = fmaf(v[t], lo.y, a1);
        a2 = fmaf(v[t], hi.x, a2);
        a3 = fmaf(v[t], hi.y, a3);
    }
}

__device__ __forceinline__ void spmm_row_q(const int2* __restrict__ edges,
                                           const unsigned* __restrict__ tab,
                                           int s, int n, int g, int li,
                                           float& a0, float& a1, float& a2, float& a3) {
    int nq = n >> 2, rem = n & 3;
    int q = 0;
    for (; q + 8 <= nq; q += 8)
        qflight<8>(edges, tab, s, q, g, li, a0, a1, a2, a3);
    if (nq - q >= 4) { qflight<4>(edges, tab, s, q, g, li, a0, a1, a2, a3); q += 4; }
    if (nq - q >= 2) { qflight<2>(edges, tab, s, q, g, li, a0, a1, a2, a3); q += 2; }
    if (nq - q >= 1) { qflight<1>(edges, tab, s, q, g, li, a0, a1, a2, a3); q += 1; }
    if (rem) {                                  // last 1-3 edges, masked
        int gi = (g < rem) ? g : 0;
        int2 e = edges[s + 4 * nq + gi];
        float v = (g < rem) ? __int_as_float(e.y) : 0.f;
        unsigned u = tab[(size_t)e.x * 16 + li];
        floatx2 lo = __builtin_amdgcn_cvt_pk_f32_fp8(u, false);
        floatx2 hi = __builtin_amdgcn_cvt_pk_f32_fp8(u, true);
        a0 = fmaf(v, lo.x, a0);
        a1 = fmaf(v, lo.y, a1);
        a2 = fmaf(v, hi.x, a2);
        a3 = fmaf(v, hi.y, a3);
    }
}

// ---------------------------------------------------------------------------
// Gather SpMM (fp8): one wave per row, quad-gather layout.
// ---------------------------------------------------------------------------
__global__ __launch_bounds__(256) void k_spmm_csr(const int* __restrict__ startArr,
                                                  const int* __restrict__ counts,
                                                  const int2* __restrict__ edges,
                                                  const unsigned* __restrict__ cur,
                                                  unsigned* __restrict__ nxt) {
    int row  = blockIdx.x * 4 + (threadIdx.x >> 6);
    if (row >= N_NODES) return;
    row = __builtin_amdgcn_readfirstlane(row);
    int lane = threadIdx.x & 63;
    int g  = lane >> 4;
    int li = lane & 15;
    int s = __builtin_amdgcn_readfirstlane(startArr[row]);
    int n = __builtin_amdgcn_readfirstlane(counts[row]);

    float a0 = 0.f, a1 = 0.f, a2 = 0.f, a3 = 0.f;
    spmm_row_q(edges, cur, s, n, g, li, a0, a1, a2, a3);

    // combine the 4 edge-groups (butterfly over lane^16, lane^32)
    a0 += __shfl_xor(a0, 16); a0 += __shfl_xor(a0, 32);
    a1 += __shfl_xor(a1, 16); a1 += __shfl_xor(a1, 32);
    a2 += __shfl_xor(a2, 16); a2 += __shfl_xor(a2, 32);
    a3 += __shfl_xor(a3, 16); a3 += __shfl_xor(a3, 32);
    if (g == 0)
        nxt[(size_t)row * 16 + li] = pk4_fp8(a0, a1, a2, a3);
}

// ---------------------------------------------------------------------------
// Fused layer-3 + layer-2 gather_add at selected rows (quad layout, fp8).
// ---------------------------------------------------------------------------
__global__ __launch_bounds__(256) void k_spmm_sel(const int* __restrict__ users,
                                                  const int* __restrict__ items,
                                                  const int* __restrict__ startArr,
                                                  const int* __restrict__ counts,
                                                  const int2* __restrict__ edges,
                                                  const unsigned* __restrict__ cur,
                                                  float* __restrict__ vsel) {
    int wave = blockIdx.x * 4 + (threadIdx.x >> 6);
    int lane = threadIdx.x & 63;
    int g  = lane >> 4;
    int li = lane & 15;
    int b, row, off;
    if (wave < BATCH) { b = wave;         row = users[b];             off = 0; }
    else              { b = wave - BATCH; row = NUM_USERS + items[b]; off = 64; }
    row = __builtin_amdgcn_readfirstlane(row);
    int s = __builtin_amdgcn_readfirstlane(startArr[row]);
    int n = __builtin_amdgcn_readfirstlane(counts[row]);

    float a0 = 0.f, a1 = 0.f, a2 = 0.f, a3 = 0.f;
    if (g == 0) {                          // layer-2 contribution (once)
        unsigned u = cur[(size_t)row * 16 + li];
        floatx2 lo = __builtin_amdgcn_cvt_pk_f32_fp8(u, false);
        floatx2 hi = __builtin_amdgcn_cvt_pk_f32_fp8(u, true);
        a0 = lo.x; a1 = lo.y; a2 = hi.x; a3 = hi.y;
    }
    spmm_row_q(edges, cur, s, n, g, li, a0, a1, a2, a3);

    a0 += __shfl_xor(a0, 16); a0 += __shfl_xor(a0, 32);
    a1 += __shfl_xor(a1, 16); a1 += __shfl_xor(a1, 32);
    a2 += __shfl_xor(a2, 16); a2 += __shfl_xor(a2, 32);
    a3 += __shfl_xor(a3, 16); a3 += __shfl_xor(a3, 32);
    if (g == 0) {
        float4* p = (float4*)(vsel + (size_t)b * 128 + off) + li;
        float4 t = *p;
        t.x += a0; t.y += a1; t.z += a2; t.w += a3;
        *p = t;
    }
}

// ---------------------------------------------------------------------------
// vsel += fp8 src at selected rows (after layer 1). One thread = 4 dims.
// ---------------------------------------------------------------------------
__global__ void k_gather_add(const int* __restrict__ users,
                             const int* __restrict__ items,
                             const unsigned* __restrict__ src,
                             float* __restrict__ vsel) {
    int t = blockIdx.x * blockDim.x + threadIdx.x;   // BATCH*16 threads
    int b = t >> 4, li = t & 15;
    unsigned uu = src[(size_t)users[b] * 16 + li];
    unsigned iu = src[(size_t)(NUM_USERS + items[b]) * 16 + li];
    floatx2 ulo = __builtin_amdgcn_cvt_pk_f32_fp8(uu, false);
    floatx2 uhi = __builtin_amdgcn_cvt_pk_f32_fp8(uu, true);
    floatx2 ilo = __builtin_amdgcn_cvt_pk_f32_fp8(iu, false);
    floatx2 ihi = __builtin_amdgcn_cvt_pk_f32_fp8(iu, true);
    float4* pu = (float4*)(vsel + (size_t)b * 128) + li;
    float4 a = *pu;
    a.x += ulo.x; a.y += ulo.y; a.z += uhi.x; a.w += uhi.y;
    *pu = a;
    float4* pi = (float4*)(vsel + (size_t)b * 128 + 64) + li;
    float4 c = *pi;
    c.x += ilo.x; c.y += ilo.y; c.z += ihi.x; c.w += ihi.y;
    *pi = c;
}

// ---------------------------------------------------------------------------
// MLP head v2: one THREAD per batch row, no cross-lane ops.
// ---------------------------------------------------------------------------
__global__ __launch_bounds__(256) void k_mlp(const float* __restrict__ vsel,
                                             const float* __restrict__ W0,
                                             const float* __restrict__ b0,
                                             const float* __restrict__ W1,
                                             const float* __restrict__ b1,
                                             const float* __restrict__ Wa,
                                             const float* __restrict__ ba,
                                             float* __restrict__ out) {
    __shared__ float sW0[128 * 64];
    __shared__ float sW1[64 * 32];
    __shared__ float sWa[32];
    __shared__ float sb0[64];
    __shared__ float sb1[32];

    for (int i = threadIdx.x; i < 128 * 64; i += 256) sW0[i] = W0[i];
    for (int i = threadIdx.x; i < 64 * 32;  i += 256) sW1[i] = W1[i];
    if (threadIdx.x < 32) sWa[threadIdx.x] = Wa[threadIdx.x];
    if (threadIdx.x < 64) sb0[threadIdx.x] = b0[threadIdx.x];
    if (threadIdx.x >= 64 && threadIdx.x < 96) sb1[threadIdx.x - 64] = b1[threadIdx.x - 64];
    float sba = ba[0];
    __syncthreads();

    int b = blockIdx.x * 256 + threadIdx.x;          // one row per thread
    const float4* v4 = (const float4*)(vsel + (size_t)b * 128);

    float h0[64];
    #pragma unroll
    for (int j = 0; j < 64; j++) h0[j] = sb0[j];

    for (int k0 = 0; k0 < 32; k0++) {                // 32 float4 = 128 inputs
        float4 va = v4[k0];
        float a0 = va.x * 0.25f, a1 = va.y * 0.25f;
        float a2 = va.z * 0.25f, a3 = va.w * 0.25f;
        const float* w = &sW0[(k0 * 4) * 64];
        #pragma unroll
        for (int j = 0; j < 64; j++) {
            h0[j] = fmaf(a0, w[j],       h0[j]);
            h0[j] = fmaf(a1, w[64 + j],  h0[j]);
            h0[j] = fmaf(a2, w[128 + j], h0[j]);
            h0[j] = fmaf(a3, w[192 + j], h0[j]);
        }
    }
    #pragma unroll
    for (int j = 0; j < 64; j++) h0[j] = fmaxf(h0[j], 0.f);

    float h1[32];
    #pragma unroll
    for (int j = 0; j < 32; j++) h1[j] = sb1[j];
    for (int k = 0; k < 64; k++) {
        float a = h0[k];
        const float* w = &sW1[k * 32];
        #pragma unroll
        for (int j = 0; j < 32; j++)
            h1[j] = fmaf(a, w[j], h1[j]);
    }

    float logit = sba;
    #pragma unroll
    for (int j = 0; j < 32; j++)
        logit = fmaf(fmaxf(h1[j], 0.f), sWa[j], logit);

    out[b] = 1.0f / (1.0f + expf(-logit));
}

// ---------------------------------------------------------------------------
extern "C" void kernel_launch(void* const* d_in, const int* in_sizes, int n_in,
                              void* d_out, int out_size, void* d_ws, size_t ws_size,
                              hipStream_t stream) {
    const int*   users = (const int*)  d_in[0];
    const int*   items = (const int*)  d_in[1];
    const int*   rows  = (const int*)  d_in[2];
    const int*   cols  = (const int*)  d_in[3];
    const float* vals  = (const float*)d_in[4];
    const float* ue    = (const float*)d_in[5];
    const float* ie    = (const float*)d_in[6];
    const float* W0    = (const float*)d_in[7];
    const float* b0    = (const float*)d_in[8];
    const float* W1    = (const float*)d_in[9];
    const float* b1    = (const float*)d_in[10];
    const float* Wa    = (const float*)d_in[11];
    const float* ba    = (const float*)d_in[12];
    float* out = (float*)d_out;

    char* ws = (char*)d_ws;
    unsigned* tabA8 = (unsigned*)ws;  ws += (size_t)N_NODES * 64;                // 9.6 MB
    unsigned* tabB8 = (unsigned*)ws;  ws += (size_t)N_NODES * 64;                // 9.6 MB
    float* vsel = (float*)ws;         ws += (size_t)BATCH * 128 * 4;             // 8.39 MB
    int2*  edges  = (int2*)ws;        ws += (size_t)N_EDGES * 8;                 // 19.2 MB
    int2*  staged = (int2*)ws;        ws += (size_t)N_EDGES * 8;                 // 19.2 MB
    int* counts   = (int*)ws;         ws += N_NODES * 4;
    int* startArr = (int*)ws;         ws += N_NODES * 4;
    int* cmat     = (int*)ws;         ws += (size_t)NBKT * NBLK * 4;             // 686 KB
    int* btotal   = (int*)ws;         ws += NBKT * 4;
    int* bbase    = (int*)ws;         ws += (NBKT + 1) * 4;

    // fp8 table + fp32 layer-0 selection
    k_concat_fp8<<<(N_NODES * 16 + 255) / 256, 256, 0, stream>>>(
        (const float4*)ue, (const float4*)ie, tabA8);
    k_sel_init<<<(BATCH * 64) / 256, 256, 0, stream>>>(users, items, ue, ie, vsel);

    // ---- CSR build: zero global atomics, no row histogram ----
    k_p1a<<<NBLK, 256, 0, stream>>>(rows, cmat);
    k_p1b<<<NBKT, 1024, 0, stream>>>(cmat, btotal);
    k_bscan<<<1, 512, 0, stream>>>(btotal, bbase);
    k_p1c<<<NBLK, 256, 0, stream>>>(rows, cols, vals, cmat, bbase, staged);
    k_p2<<<NBKT, 256, 0, stream>>>(bbase, staged, edges, counts, startArr);

    // layer 1: A -> B (writes every row; no memset needed)
    k_spmm_csr<<<(N_NODES + 3) / 4, 256, 0, stream>>>(startArr, counts, edges, tabA8, tabB8);
    k_gather_add<<<(BATCH * 16) / 256, 256, 0, stream>>>(users, items, tabB8, vsel);

    // layer 2: B -> A
    k_spmm_csr<<<(N_NODES + 3) / 4, 256, 0, stream>>>(startArr, counts, edges, tabB8, tabA8);

    // layer 3 (selected rows only) fused with layer-2 gather_add
    k_spmm_sel<<<(2 * BATCH) / 4, 256, 0, stream>>>(users, items, startArr,
                                                    counts, edges, tabA8, vsel);

    // MLP head: one thread per row
    k_mlp<<<BATCH / 256, 256, 0, stream>>>(vsel, W0, b0, W1, b1, Wa, ba, out);
}

// Round 3
// 341.075 us; speedup vs baseline: 1.1219x; 1.0752x over previous
//
#include <hip/hip_runtime.h>
#include <math.h>

#define NUM_USERS 100000
#define NUM_ITEMS 50000
#define N_NODES   150000   // NUM_USERS + NUM_ITEMS
#define LATENT    64
#define N_EDGES   2400000
#define BATCH     16384

// Multisplit fill: 4096-edge chunks, 512-row buckets
#define CHUNK 4096
#define NBLK  ((N_EDGES + CHUNK - 1) / CHUNK)   // 586
#define NBKT  ((N_NODES + 511) / 512)           // 293

typedef __attribute__((ext_vector_type(2))) float floatx2;

// fp8 e4m3 pack/unpack via gfx950 HW converters (encode+decode self-consistent)
__device__ __forceinline__ unsigned pk4_fp8(float a, float b, float c, float d) {
    int u = __builtin_amdgcn_cvt_pk_fp8_f32(a, b, 0, false);
    u     = __builtin_amdgcn_cvt_pk_fp8_f32(c, d, u, true);
    return (unsigned)u;
}

// ---------------------------------------------------------------------------
// Fused prep: [blocks 0..9374]   tab = fp8(concat(user_emb, item_emb))
//             [blocks 9375..]    vsel layer-0 fp32 selection
// ---------------------------------------------------------------------------
#define CONCAT_BLKS ((N_NODES * 16) / 256)      // 9375
__global__ __launch_bounds__(256) void k_prep(const float4* __restrict__ ue4,
                                              const float4* __restrict__ ie4,
                                              unsigned* __restrict__ tab,
                                              const int* __restrict__ users,
                                              const int* __restrict__ items,
                                              const float* __restrict__ ue,
                                              const float* __restrict__ ie,
                                              float* __restrict__ vsel) {
    if (blockIdx.x < CONCAT_BLKS) {
        int i = blockIdx.x * 256 + threadIdx.x;
        const int nU4 = NUM_USERS * 16;
        float4 v = (i < nU4) ? ue4[i] : ie4[i - nU4];
        tab[i] = pk4_fp8(v.x, v.y, v.z, v.w);
    } else {
        int t = (blockIdx.x - CONCAT_BLKS) * 256 + threadIdx.x;
        int b = t >> 6, d = t & 63;
        vsel[b * 128 + d]      = ue[users[b] * 64 + d];
        vsel[b * 128 + 64 + d] = ie[items[b] * 64 + d];
    }
}

// ---------------------------------------------------------------------------
// Multisplit p1a: per-block bucket histogram -> cmat[bucket][block]
// ---------------------------------------------------------------------------
__global__ __launch_bounds__(256) void k_p1a(const int* __restrict__ rows,
                                             int* __restrict__ cmat) {
    __shared__ int hist[NBKT];
    for (int i = threadIdx.x; i < NBKT; i += 256) hist[i] = 0;
    __syncthreads();
    int e0 = blockIdx.x * CHUNK;
    int cnt = min(CHUNK, N_EDGES - e0);              // 4096 or 3840: %4 == 0
    const int4* r4 = (const int4*)(rows + e0);
    for (int t = threadIdx.x; t < (cnt >> 2); t += 256) {
        int4 r = r4[t];
        atomicAdd(&hist[r.x >> 9], 1);
        atomicAdd(&hist[r.y >> 9], 1);
        atomicAdd(&hist[r.z >> 9], 1);
        atomicAdd(&hist[r.w >> 9], 1);
    }
    __syncthreads();
    for (int i = threadIdx.x; i < NBKT; i += 256)
        cmat[i * NBLK + blockIdx.x] = hist[i];
}

// ---------------------------------------------------------------------------
// Multisplit p1b: per-bucket exclusive scan over blocks (hierarchical wave
// scan: 2 barriers instead of 20). Saves raw counts to bcnt for p1c; emits
// bucket total.
// ---------------------------------------------------------------------------
__global__ __launch_bounds__(1024) void k_p1b(int* __restrict__ cmat,
                                              int* __restrict__ bcnt,
                                              int* __restrict__ btotal) {
    __shared__ int wsum[16];
    int k = blockIdx.x;
    int tid = threadIdx.x;
    int lane = tid & 63, wid = tid >> 6;
    int v = (tid < NBLK) ? cmat[k * NBLK + tid] : 0;
    if (tid < NBLK) bcnt[k * NBLK + tid] = v;        // raw counts for p1c
    // wave-inclusive scan
    int x = v;
    #pragma unroll
    for (int d = 1; d < 64; d <<= 1) {
        int y = __shfl_up(x, d);
        if (lane >= d) x += y;
    }
    if (lane == 63) wsum[wid] = x;
    __syncthreads();
    if (wid == 0 && lane < 16) {
        int w = wsum[lane];
        #pragma unroll
        for (int d = 1; d < 16; d <<= 1) {
            int y = __shfl_up(w, d);
            if (lane >= d) w += y;
        }
        wsum[lane] = w;
    }
    __syncthreads();
    int incl = x + (wid ? wsum[wid - 1] : 0);
    if (tid < NBLK) cmat[k * NBLK + tid] = incl - v; // exclusive
    if (tid == 1023) btotal[k] = incl;               // padding adds 0
}

// ---------------------------------------------------------------------------
// Bucket-base scan: exclusive scan of 293 bucket totals -> bbase[0..NBKT]
// ---------------------------------------------------------------------------
__global__ __launch_bounds__(512) void k_bscan(const int* __restrict__ btotal,
                                               int* __restrict__ bbase) {
    __shared__ int sh[512];
    int v = (threadIdx.x < NBKT) ? btotal[threadIdx.x] : 0;
    sh[threadIdx.x] = v;
    __syncthreads();
    for (int off = 1; off < 512; off <<= 1) {
        int t = (threadIdx.x >= off) ? sh[threadIdx.x - off] : 0;
        __syncthreads();
        sh[threadIdx.x] += t;
        __syncthreads();
    }
    if (threadIdx.x < NBKT) bbase[threadIdx.x] = sh[threadIdx.x] - v;
    if (threadIdx.x == NBKT) bbase[NBKT] = N_EDGES;
}

// ---------------------------------------------------------------------------
// Multisplit p1c: bin records in LDS using p1b's saved counts (no re-
// histogram, no rows re-read for counting), flush bucket-contiguous runs
// at exact offsets (cmat + bbase). Zero global atomics.
// Record: x = col(18b) | rowLo(9b)<<18 ; y = fp32 val bits.
// ---------------------------------------------------------------------------
__global__ __launch_bounds__(256) void k_p1c(const int* __restrict__ rows,
                                             const int* __restrict__ cols,
                                             const float* __restrict__ vals,
                                             const int* __restrict__ offs,
                                             const int* __restrict__ bcnt,
                                             const int* __restrict__ bbase,
                                             int2* __restrict__ staged) {
    __shared__ int hist[NBKT];
    __shared__ int lstart[NBKT];
    __shared__ int cursor[NBKT];
    __shared__ int soffs[NBKT];
    __shared__ int sc[512];
    __shared__ int2 st[CHUNK];
    __shared__ unsigned short bkt16[CHUNK];

    int e0 = blockIdx.x * CHUNK;
    int cnt = min(CHUNK, N_EDGES - e0);              // %4 == 0 always
    for (int i = threadIdx.x; i < NBKT; i += 256) {
        hist[i] = bcnt[i * NBLK + blockIdx.x];       // from p1b
        cursor[i] = 0;
        soffs[i] = offs[i * NBLK + blockIdx.x] + bbase[i];
    }
    sc[threadIdx.x] = 0; sc[threadIdx.x + 256] = 0;
    __syncthreads();
    for (int i = threadIdx.x; i < NBKT; i += 256) sc[i] = hist[i];
    __syncthreads();
    // inclusive scan over 512 slots (256 threads x 2, Hillis-Steele)
    for (int off = 1; off < 512; off <<= 1) {
        int a0 = (threadIdx.x >= off)       ? sc[threadIdx.x - off]       : 0;
        int a1 = (threadIdx.x + 256 >= off) ? sc[threadIdx.x + 256 - off] : 0;
        __syncthreads();
        sc[threadIdx.x]       += a0;
        sc[threadIdx.x + 256] += a1;
        __syncthreads();
    }
    for (int i = threadIdx.x; i < NBKT; i += 256) lstart[i] = sc[i] - hist[i];
    __syncthreads();
    // bin into LDS staging (vectorized 4-edge input stream)
    const int4*   r4 = (const int4*)  (rows + e0);
    const int4*   c4 = (const int4*)  (cols + e0);
    const float4* v4 = (const float4*)(vals + e0);
    for (int t = threadIdx.x; t < (cnt >> 2); t += 256) {
        int4 r = r4[t];
        int4 c = c4[t];
        float4 v = v4[t];
        int b0 = r.x >> 9, b1 = r.y >> 9, b2 = r.z >> 9, b3 = r.w >> 9;
        int p0 = lstart[b0] + atomicAdd(&cursor[b0], 1);
        st[p0] = make_int2(c.x | ((r.x & 511) << 18), __float_as_int(v.x));
        bkt16[p0] = (unsigned short)b0;
        int p1 = lstart[b1] + atomicAdd(&cursor[b1], 1);
        st[p1] = make_int2(c.y | ((r.y & 511) << 18), __float_as_int(v.y));
        bkt16[p1] = (unsigned short)b1;
        int p2 = lstart[b2] + atomicAdd(&cursor[b2], 1);
        st[p2] = make_int2(c.z | ((r.z & 511) << 18), __float_as_int(v.z));
        bkt16[p2] = (unsigned short)b2;
        int p3 = lstart[b3] + atomicAdd(&cursor[b3], 1);
        st[p3] = make_int2(c.w | ((r.w & 511) << 18), __float_as_int(v.w));
        bkt16[p3] = (unsigned short)b3;
    }
    __syncthreads();
    // flush: consecutive threads in a bucket write consecutive global addrs
    for (int t = threadIdx.x; t < cnt; t += 256) {
        int b = bkt16[t];
        staged[soffs[b] + (t - lstart[b])] = st[t];
    }
}

// ---------------------------------------------------------------------------
// Multisplit p2: one block per bucket; row histogram from staged records,
// LDS scan -> local row starts, place records, emit counts/startArr.
// ---------------------------------------------------------------------------
__global__ __launch_bounds__(256) void k_p2(const int* __restrict__ bbase,
                                            const int2* __restrict__ staged,
                                            int2* __restrict__ edges,
                                            int* __restrict__ counts,
                                            int* __restrict__ startArr) {
    __shared__ int hist[512];
    __shared__ int lstart[512];
    __shared__ int cur[512];
    __shared__ int sc[512];
    int k = blockIdx.x;
    int rowBase = k << 9;
    int numRows = min(512, N_NODES - rowBase);
    int base = bbase[k];
    int end  = bbase[k + 1];
    hist[threadIdx.x] = 0;       hist[threadIdx.x + 256] = 0;
    cur[threadIdx.x] = 0;        cur[threadIdx.x + 256] = 0;
    __syncthreads();
    int cnt = end - base;
    for (int t = threadIdx.x; t < cnt; t += 256)
        atomicAdd(&hist[((unsigned)staged[base + t].x) >> 18], 1);
    __syncthreads();
    sc[threadIdx.x] = hist[threadIdx.x];
    sc[threadIdx.x + 256] = hist[threadIdx.x + 256];
    __syncthreads();
    for (int off = 1; off < 512; off <<= 1) {
        int a0 = (threadIdx.x >= off)       ? sc[threadIdx.x - off]       : 0;
        int a1 = (threadIdx.x + 256 >= off) ? sc[threadIdx.x + 256 - off] : 0;
        __syncthreads();
        sc[threadIdx.x]       += a0;
        sc[threadIdx.x + 256] += a1;
        __syncthreads();
    }
    lstart[threadIdx.x]       = sc[threadIdx.x]       - hist[threadIdx.x];
    lstart[threadIdx.x + 256] = sc[threadIdx.x + 256] - hist[threadIdx.x + 256];
    __syncthreads();
    for (int t = threadIdx.x; t < cnt; t += 256) {
        int2 rec = staged[base + t];
        int rl = ((unsigned)rec.x) >> 18;
        int c  = rec.x & 0x3FFFF;
        int off = lstart[rl] + atomicAdd(&cur[rl], 1);
        edges[base + off] = make_int2(c, rec.y);
    }
    for (int i = threadIdx.x; i < numRows; i += 256) {
        counts[rowBase + i]   = hist[i];
        startArr[rowBase + i] = base + lstart[i];
    }
}

// ---------------------------------------------------------------------------
// Quad-gather SpMM core (fp8 table).
// 64 lanes = 4 groups of 16; group g handles edges 4q+g. Lane li in a group
// reads one uint (4 fp8 dims) -> 16 lanes cover the 64 B row. ONE vmem
// instruction fetches FOUR edges' rows. Bound by TCP miss slots (~1 row-miss
// per edge per ~14.5 cy/CU) -- at the structural floor; do not grow flights.
// ---------------------------------------------------------------------------
template<int P>
__device__ __forceinline__ void qflight(const int2* __restrict__ edges,
                                        const unsigned* __restrict__ tab,
                                        int s, int q, int g, int li,
                                        float& a0, float& a1, float& a2, float& a3) {
    unsigned u[P];
    float    v[P];
    #pragma unroll
    for (int t = 0; t < P; t++) {
        int2 e = edges[s + 4 * (q + t) + g];   // 16 lanes share addr -> 1 line
        v[t] = __int_as_float(e.y);
        u[t] = tab[(size_t)e.x * 16 + li];     // 16 lanes x 4B = full 64B row
    }
    #pragma unroll
    for (int t = 0; t < P; t++) {
        floatx2 lo = __builtin_amdgcn_cvt_pk_f32_fp8(u[t], false);
        floatx2 hi = __builtin_amdgcn_cvt_pk_f32_fp8(u[t], true);
        a0 = fmaf(v[t], lo.x, a0);
        a1 = fmaf(v[t], lo.y, a1);
        a2 = fmaf(v[t], hi.x, a2);
        a3 = fmaf(v[t], hi.y, a3);
    }
}

__device__ __forceinline__ void spmm_row_q(const int2* __restrict__ edges,
                                           const unsigned* __restrict__ tab,
                                           int s, int n, int g, int li,
                                           float& a0, float& a1, float& a2, float& a3) {
    int nq = n >> 2, rem = n & 3;
    int q = 0;
    for (; q + 8 <= nq; q += 8)
        qflight<8>(edges, tab, s, q, g, li, a0, a1, a2, a3);
    if (nq - q >= 4) { qflight<4>(edges, tab, s, q, g, li, a0, a1, a2, a3); q += 4; }
    if (nq - q >= 2) { qflight<2>(edges, tab, s, q, g, li, a0, a1, a2, a3); q += 2; }
    if (nq - q >= 1) { qflight<1>(edges, tab, s, q, g, li, a0, a1, a2, a3); q += 1; }
    if (rem) {                                  // last 1-3 edges, masked
        int gi = (g < rem) ? g : 0;
        int2 e = edges[s + 4 * nq + gi];
        float v = (g < rem) ? __int_as_float(e.y) : 0.f;
        unsigned u = tab[(size_t)e.x * 16 + li];
        floatx2 lo = __builtin_amdgcn_cvt_pk_f32_fp8(u, false);
        floatx2 hi = __builtin_amdgcn_cvt_pk_f32_fp8(u, true);
        a0 = fmaf(v, lo.x, a0);
        a1 = fmaf(v, lo.y, a1);
        a2 = fmaf(v, hi.x, a2);
        a3 = fmaf(v, hi.y, a3);
    }
}

// ---------------------------------------------------------------------------
// Gather SpMM (fp8): one wave per row, quad-gather layout.
// ---------------------------------------------------------------------------
__global__ __launch_bounds__(256) void k_spmm_csr(const int* __restrict__ startArr,
                                                  const int* __restrict__ counts,
                                                  const int2* __restrict__ edges,
                                                  const unsigned* __restrict__ cur,
                                                  unsigned* __restrict__ nxt) {
    int row  = blockIdx.x * 4 + (threadIdx.x >> 6);
    if (row >= N_NODES) return;
    row = __builtin_amdgcn_readfirstlane(row);
    int lane = threadIdx.x & 63;
    int g  = lane >> 4;
    int li = lane & 15;
    int s = __builtin_amdgcn_readfirstlane(startArr[row]);
    int n = __builtin_amdgcn_readfirstlane(counts[row]);

    float a0 = 0.f, a1 = 0.f, a2 = 0.f, a3 = 0.f;
    spmm_row_q(edges, cur, s, n, g, li, a0, a1, a2, a3);

    // combine the 4 edge-groups (butterfly over lane^16, lane^32)
    a0 += __shfl_xor(a0, 16); a0 += __shfl_xor(a0, 32);
    a1 += __shfl_xor(a1, 16); a1 += __shfl_xor(a1, 32);
    a2 += __shfl_xor(a2, 16); a2 += __shfl_xor(a2, 32);
    a3 += __shfl_xor(a3, 16); a3 += __shfl_xor(a3, 32);
    if (g == 0)
        nxt[(size_t)row * 16 + li] = pk4_fp8(a0, a1, a2, a3);
}

// ---------------------------------------------------------------------------
// Fused layer-3 gathers + layer-2 + layer-1 contributions at selected rows.
// (tabB8 = layer-1 output is still intact here; layer-2 wrote tabA8.)
// ---------------------------------------------------------------------------
__global__ __launch_bounds__(256) void k_spmm_sel(const int* __restrict__ users,
                                                  const int* __restrict__ items,
                                                  const int* __restrict__ startArr,
                                                  const int* __restrict__ counts,
                                                  const int2* __restrict__ edges,
                                                  const unsigned* __restrict__ cur,
                                                  const unsigned* __restrict__ lay1,
                                                  float* __restrict__ vsel) {
    int wave = blockIdx.x * 4 + (threadIdx.x >> 6);
    int lane = threadIdx.x & 63;
    int g  = lane >> 4;
    int li = lane & 15;
    int b, row, off;
    if (wave < BATCH) { b = wave;         row = users[b];             off = 0; }
    else              { b = wave - BATCH; row = NUM_USERS + items[b]; off = 64; }
    row = __builtin_amdgcn_readfirstlane(row);
    int s = __builtin_amdgcn_readfirstlane(startArr[row]);
    int n = __builtin_amdgcn_readfirstlane(counts[row]);

    float a0 = 0.f, a1 = 0.f, a2 = 0.f, a3 = 0.f;
    if (g == 0) {                          // layer-2 + layer-1 contributions
        unsigned u2 = cur [(size_t)row * 16 + li];
        unsigned u1 = lay1[(size_t)row * 16 + li];
        floatx2 lo2 = __builtin_amdgcn_cvt_pk_f32_fp8(u2, false);
        floatx2 hi2 = __builtin_amdgcn_cvt_pk_f32_fp8(u2, true);
        floatx2 lo1 = __builtin_amdgcn_cvt_pk_f32_fp8(u1, false);
        floatx2 hi1 = __builtin_amdgcn_cvt_pk_f32_fp8(u1, true);
        a0 = lo2.x + lo1.x; a1 = lo2.y + lo1.y;
        a2 = hi2.x + hi1.x; a3 = hi2.y + hi1.y;
    }
    spmm_row_q(edges, cur, s, n, g, li, a0, a1, a2, a3);

    a0 += __shfl_xor(a0, 16); a0 += __shfl_xor(a0, 32);
    a1 += __shfl_xor(a1, 16); a1 += __shfl_xor(a1, 32);
    a2 += __shfl_xor(a2, 16); a2 += __shfl_xor(a2, 32);
    a3 += __shfl_xor(a3, 16); a3 += __shfl_xor(a3, 32);
    if (g == 0) {
        float4* p = (float4*)(vsel + (size_t)b * 128 + off) + li;
        float4 t = *p;
        t.x += a0; t.y += a1; t.z += a2; t.w += a3;
        *p = t;
    }
}

// ---------------------------------------------------------------------------
// MLP head v3: 4 threads per batch row (k-split), shfl_xor reduction.
// Grid 256 blocks x 256 threads = 65536 threads -> all 256 CUs busy
// (v2 used 64 blocks -> only 64 CUs).
// ---------------------------------------------------------------------------
__global__ __launch_bounds__(256) void k_mlp(const float* __restrict__ vsel,
                                             const float* __restrict__ W0,
                                             const float* __restrict__ b0,
                                             const float* __restrict__ W1,
                                             const float* __restrict__ b1,
                                             const float* __restrict__ Wa,
                                             const float* __restrict__ ba,
                                             float* __restrict__ out) {
    __shared__ float sW0[128 * 64];
    __shared__ float sW1[64 * 32];
    __shared__ float sWa[32];
    __shared__ float sb0[64];
    __shared__ float sb1[32];

    for (int i = threadIdx.x; i < 128 * 64; i += 256) sW0[i] = W0[i];
    for (int i = threadIdx.x; i < 64 * 32;  i += 256) sW1[i] = W1[i];
    if (threadIdx.x < 32) sWa[threadIdx.x] = Wa[threadIdx.x];
    if (threadIdx.x < 64) sb0[threadIdx.x] = b0[threadIdx.x];
    if (threadIdx.x >= 64 && threadIdx.x < 96) sb1[threadIdx.x - 64] = b1[threadIdx.x - 64];
    float sba = ba[0];
    __syncthreads();

    int t = blockIdx.x * 256 + threadIdx.x;
    int b = t >> 2, sub = t & 3;                     // 4 threads per row
    const float4* v4 = (const float4*)(vsel + (size_t)b * 128) + sub * 8;

    float h0[64];
    #pragma unroll
    for (int j = 0; j < 64; j++) h0[j] = 0.f;

    for (int k0 = 0; k0 < 8; k0++) {                 // 8 float4 = 32 of 128 in
        float4 va = v4[k0];
        float a0 = va.x * 0.25f, a1 = va.y * 0.25f;
        float a2 = va.z * 0.25f, a3 = va.w * 0.25f;
        const float* w = &sW0[(sub * 32 + k0 * 4) * 64];
        #pragma unroll
        for (int j = 0; j < 64; j++) {
            h0[j] = fmaf(a0, w[j],       h0[j]);
            h0[j] = fmaf(a1, w[64 + j],  h0[j]);
            h0[j] = fmaf(a2, w[128 + j], h0[j]);
            h0[j] = fmaf(a3, w[192 + j], h0[j]);
        }
    }
    // reduce partials across the 4 subs (quad stays inside the wave)
    #pragma unroll
    for (int j = 0; j < 64; j++) {
        h0[j] += __shfl_xor(h0[j], 1);
        h0[j] += __shfl_xor(h0[j], 2);
        h0[j] = fmaxf(h0[j] + sb0[j], 0.f);
    }

    float h1[32];
    #pragma unroll
    for (int j = 0; j < 32; j++) h1[j] = 0.f;
    for (int k = 0; k < 16; k++) {                   // k-split of 64 by 4
        float a = h0[sub * 16 + k];
        const float* w = &sW1[(sub * 16 + k) * 32];
        #pragma unroll
        for (int j = 0; j < 32; j++)
            h1[j] = fmaf(a, w[j], h1[j]);
    }
    #pragma unroll
    for (int j = 0; j < 32; j++) {
        h1[j] += __shfl_xor(h1[j], 1);
        h1[j] += __shfl_xor(h1[j], 2);
    }

    float logit = sba;
    #pragma unroll
    for (int j = 0; j < 32; j++)
        logit = fmaf(fmaxf(h1[j] + sb1[j], 0.f), sWa[j], logit);

    if (sub == 0) out[b] = 1.0f / (1.0f + expf(-logit));
}

// ---------------------------------------------------------------------------
extern "C" void kernel_launch(void* const* d_in, const int* in_sizes, int n_in,
                              void* d_out, int out_size, void* d_ws, size_t ws_size,
                              hipStream_t stream) {
    const int*   users = (const int*)  d_in[0];
    const int*   items = (const int*)  d_in[1];
    const int*   rows  = (const int*)  d_in[2];
    const int*   cols  = (const int*)  d_in[3];
    const float* vals  = (const float*)d_in[4];
    const float* ue    = (const float*)d_in[5];
    const float* ie    = (const float*)d_in[6];
    const float* W0    = (const float*)d_in[7];
    const float* b0    = (const float*)d_in[8];
    const float* W1    = (const float*)d_in[9];
    const float* b1    = (const float*)d_in[10];
    const float* Wa    = (const float*)d_in[11];
    const float* ba    = (const float*)d_in[12];
    float* out = (float*)d_out;

    char* ws = (char*)d_ws;
    unsigned* tabA8 = (unsigned*)ws;  ws += (size_t)N_NODES * 64;                // 9.6 MB
    unsigned* tabB8 = (unsigned*)ws;  ws += (size_t)N_NODES * 64;                // 9.6 MB
    float* vsel = (float*)ws;         ws += (size_t)BATCH * 128 * 4;             // 8.39 MB
    int2*  edges  = (int2*)ws;        ws += (size_t)N_EDGES * 8;                 // 19.2 MB
    int2*  staged = (int2*)ws;        ws += (size_t)N_EDGES * 8;                 // 19.2 MB
    int* counts   = (int*)ws;         ws += N_NODES * 4;
    int* startArr = (int*)ws;         ws += N_NODES * 4;
    int* cmat     = (int*)ws;         ws += (size_t)NBKT * NBLK * 4;             // 686 KB
    int* bcnt     = (int*)ws;         ws += (size_t)NBKT * NBLK * 4;             // 686 KB
    int* btotal   = (int*)ws;         ws += NBKT * 4;
    int* bbase    = (int*)ws;         ws += (NBKT + 1) * 4;

    // fp8 table + fp32 layer-0 selection (fused, one dispatch)
    k_prep<<<CONCAT_BLKS + (BATCH * 64) / 256, 256, 0, stream>>>(
        (const float4*)ue, (const float4*)ie, tabA8, users, items, ue, ie, vsel);

    // ---- CSR build: zero global atomics ----
    k_p1a<<<NBLK, 256, 0, stream>>>(rows, cmat);
    k_p1b<<<NBKT, 1024, 0, stream>>>(cmat, bcnt, btotal);
    k_bscan<<<1, 512, 0, stream>>>(btotal, bbase);
    k_p1c<<<NBLK, 256, 0, stream>>>(rows, cols, vals, cmat, bcnt, bbase, staged);
    k_p2<<<NBKT, 256, 0, stream>>>(bbase, staged, edges, counts, startArr);

    // layer 1: A -> B (writes every row; no memset needed)
    k_spmm_csr<<<(N_NODES + 3) / 4, 256, 0, stream>>>(startArr, counts, edges, tabA8, tabB8);

    // layer 2: B -> A  (tabB8 stays intact for the fused sel below)
    k_spmm_csr<<<(N_NODES + 3) / 4, 256, 0, stream>>>(startArr, counts, edges, tabB8, tabA8);

    // layer 3 gathers + layer-2 + layer-1 adds at selected rows (fused)
    k_spmm_sel<<<(2 * BATCH) / 4, 256, 0, stream>>>(users, items, startArr,
                                                    counts, edges, tabA8, tabB8, vsel);

    // MLP head: 4 threads per row, all CUs
    k_mlp<<<(BATCH * 4) / 256, 256, 0, stream>>>(vsel, W0, b0, W1, b1, Wa, ba, out);
}

// Round 4
// 330.967 us; speedup vs baseline: 1.1562x; 1.0305x over previous
//
#include <hip/hip_runtime.h>
#include <math.h>

#define NUM_USERS 100000
#define NUM_ITEMS 50000
#define N_NODES   150000   // NUM_USERS + NUM_ITEMS
#define LATENT    64
#define N_EDGES   2400000
#define BATCH     16384

// Multisplit fill: 4096-edge chunks, 512-row buckets
#define CHUNK 4096
#define NBLK  ((N_EDGES + CHUNK - 1) / CHUNK)   // 586
#define NBKT  ((N_NODES + 511) / 512)           // 293

typedef __attribute__((ext_vector_type(2))) float floatx2;

// fp8 e4m3 pack/unpack via gfx950 HW converters (encode+decode self-consistent)
__device__ __forceinline__ unsigned pk4_fp8(float a, float b, float c, float d) {
    int u = __builtin_amdgcn_cvt_pk_fp8_f32(a, b, 0, false);
    u     = __builtin_amdgcn_cvt_pk_fp8_f32(c, d, u, true);
    return (unsigned)u;
}

// ---------------------------------------------------------------------------
// Inclusive wave-hierarchical scan across NT threads (3 barriers, not 18).
// wsums = LDS scratch of NT/64 ints. Entry barrier protects prior wsums use.
// ---------------------------------------------------------------------------
template<int NT>
__device__ __forceinline__ int scan_incl(int v, int tid, int* wsums) {
    int lane = tid & 63, wid = tid >> 6;
    __syncthreads();
    int x = v;
    #pragma unroll
    for (int d = 1; d < 64; d <<= 1) {
        int y = __shfl_up(x, d);
        if (lane >= d) x += y;
    }
    if (lane == 63) wsums[wid] = x;
    __syncthreads();
    constexpr int NW = NT / 64;
    if (wid == 0) {
        int w = (lane < NW) ? wsums[lane] : 0;
        #pragma unroll
        for (int d = 1; d < NW; d <<= 1) {
            int y = __shfl_up(w, d);
            if (lane >= d) w += y;
        }
        if (lane < NW) wsums[lane] = w;
    }
    __syncthreads();
    return x + (wid ? wsums[wid - 1] : 0);
}

// ---------------------------------------------------------------------------
// Fused prep: [blocks 0..NBLK-1]  p1a bucket histogram -> cmat[bucket][block]
//             [blocks NBLK.. ]    tab = fp8(concat(user_emb, item_emb))
// (independent work; single dispatch saves a full device drain)
// ---------------------------------------------------------------------------
#define CONCAT_BLKS ((N_NODES * 16) / 256)      // 9375
__global__ __launch_bounds__(256) void k_prep(const float4* __restrict__ ue4,
                                              const float4* __restrict__ ie4,
                                              unsigned* __restrict__ tab,
                                              const int* __restrict__ rows,
                                              int* __restrict__ cmat) {
    if (blockIdx.x < NBLK) {
        __shared__ int hist[NBKT];
        for (int i = threadIdx.x; i < NBKT; i += 256) hist[i] = 0;
        __syncthreads();
        int e0 = blockIdx.x * CHUNK;
        int cnt = min(CHUNK, N_EDGES - e0);          // 4096 or 3840: %4 == 0
        const int4* r4 = (const int4*)(rows + e0);
        for (int t = threadIdx.x; t < (cnt >> 2); t += 256) {
            int4 r = r4[t];
            atomicAdd(&hist[r.x >> 9], 1);
            atomicAdd(&hist[r.y >> 9], 1);
            atomicAdd(&hist[r.z >> 9], 1);
            atomicAdd(&hist[r.w >> 9], 1);
        }
        __syncthreads();
        for (int i = threadIdx.x; i < NBKT; i += 256)
            cmat[i * NBLK + blockIdx.x] = hist[i];
    } else {
        int i = (blockIdx.x - NBLK) * 256 + threadIdx.x;
        const int nU4 = NUM_USERS * 16;
        float4 v = (i < nU4) ? ue4[i] : ie4[i - nU4];
        tab[i] = pk4_fp8(v.x, v.y, v.z, v.w);
    }
}

// ---------------------------------------------------------------------------
// Multisplit p1b: per-bucket exclusive scan over blocks (hierarchical wave
// scan). Saves raw counts to bcnt for p1c; emits bucket total.
// ---------------------------------------------------------------------------
__global__ __launch_bounds__(1024) void k_p1b(int* __restrict__ cmat,
                                              int* __restrict__ bcnt,
                                              int* __restrict__ btotal) {
    __shared__ int wsum[16];
    int k = blockIdx.x;
    int tid = threadIdx.x;
    int lane = tid & 63, wid = tid >> 6;
    int v = (tid < NBLK) ? cmat[k * NBLK + tid] : 0;
    if (tid < NBLK) bcnt[k * NBLK + tid] = v;        // raw counts for p1c
    int x = v;
    #pragma unroll
    for (int d = 1; d < 64; d <<= 1) {
        int y = __shfl_up(x, d);
        if (lane >= d) x += y;
    }
    if (lane == 63) wsum[wid] = x;
    __syncthreads();
    if (wid == 0 && lane < 16) {
        int w = wsum[lane];
        #pragma unroll
        for (int d = 1; d < 16; d <<= 1) {
            int y = __shfl_up(w, d);
            if (lane >= d) w += y;
        }
        wsum[lane] = w;
    }
    __syncthreads();
    int incl = x + (wid ? wsum[wid - 1] : 0);
    if (tid < NBLK) cmat[k * NBLK + tid] = incl - v; // exclusive
    if (tid == 1023) btotal[k] = incl;               // padding adds 0
}

// ---------------------------------------------------------------------------
// Multisplit p1c (512 thr): bin records in LDS using p1b's saved counts,
// flush bucket-contiguous runs at exact offsets. Bucket bases computed
// in-LDS from btotal (no bscan kernel). Zero global atomics.
// Record: x = col(18b) | rowLo(9b)<<18 ; y = fp32 val bits.
// ---------------------------------------------------------------------------
__global__ __launch_bounds__(512) void k_p1c(const int* __restrict__ rows,
                                             const int* __restrict__ cols,
                                             const float* __restrict__ vals,
                                             const int* __restrict__ offs,
                                             const int* __restrict__ bcnt,
                                             const int* __restrict__ btotal,
                                             int2* __restrict__ staged) {
    __shared__ int hist[NBKT];
    __shared__ int lstart[NBKT];
    __shared__ int cursor[NBKT];
    __shared__ int soffs[NBKT];
    __shared__ int wsum[8];
    __shared__ int2 st[CHUNK];
    __shared__ unsigned short bkt16[CHUNK];

    int tid = threadIdx.x;
    int e0 = blockIdx.x * CHUNK;
    int cnt = min(CHUNK, N_EDGES - e0);              // %4 == 0 always

    // bucket bases from btotal (global prefix), chunk-local hist from bcnt
    int bt = (tid < NBKT) ? btotal[tid] : 0;
    int bincl = scan_incl<512>(bt, tid, wsum);       // inclusive
    int h = 0;
    if (tid < NBKT) {
        h = bcnt[tid * NBLK + blockIdx.x];
        hist[tid] = h;
        cursor[tid] = 0;
        soffs[tid] = offs[tid * NBLK + blockIdx.x] + (bincl - bt);  // + bbase
    }
    // chunk-local exclusive starts
    int hincl = scan_incl<512>(h, tid, wsum);
    if (tid < NBKT) lstart[tid] = hincl - h;
    __syncthreads();

    // bin into LDS staging (vectorized 4-edge input stream)
    const int4*   r4 = (const int4*)  (rows + e0);
    const int4*   c4 = (const int4*)  (cols + e0);
    const float4* v4 = (const float4*)(vals + e0);
    for (int t = tid; t < (cnt >> 2); t += 512) {
        int4 r = r4[t];
        int4 c = c4[t];
        float4 v = v4[t];
        int b0 = r.x >> 9, b1 = r.y >> 9, b2 = r.z >> 9, b3 = r.w >> 9;
        int p0 = lstart[b0] + atomicAdd(&cursor[b0], 1);
        st[p0] = make_int2(c.x | ((r.x & 511) << 18), __float_as_int(v.x));
        bkt16[p0] = (unsigned short)b0;
        int p1 = lstart[b1] + atomicAdd(&cursor[b1], 1);
        st[p1] = make_int2(c.y | ((r.y & 511) << 18), __float_as_int(v.y));
        bkt16[p1] = (unsigned short)b1;
        int p2 = lstart[b2] + atomicAdd(&cursor[b2], 1);
        st[p2] = make_int2(c.z | ((r.z & 511) << 18), __float_as_int(v.z));
        bkt16[p2] = (unsigned short)b2;
        int p3 = lstart[b3] + atomicAdd(&cursor[b3], 1);
        st[p3] = make_int2(c.w | ((r.w & 511) << 18), __float_as_int(v.w));
        bkt16[p3] = (unsigned short)b3;
    }
    __syncthreads();
    // flush: consecutive threads in a bucket write consecutive global addrs
    for (int t = tid; t < cnt; t += 512) {
        int b = bkt16[t];
        staged[soffs[b] + (t - lstart[b])] = st[t];
    }
}

// ---------------------------------------------------------------------------
// Multisplit p2 (512 thr): one block per bucket; bucket base from in-LDS
// btotal scan; row histogram; wave-scan -> local row starts; place records;
// emit counts/startArr.
// ---------------------------------------------------------------------------
__global__ __launch_bounds__(512) void k_p2(const int* __restrict__ btotal,
                                            const int2* __restrict__ staged,
                                            int2* __restrict__ edges,
                                            int* __restrict__ counts,
                                            int* __restrict__ startArr) {
    __shared__ int hist[512];
    __shared__ int lstart[512];
    __shared__ int curso[512];
    __shared__ int wsum[8];
    __shared__ int s_base, s_end;
    int k = blockIdx.x;
    int tid = threadIdx.x;
    int rowBase = k << 9;
    int numRows = min(512, N_NODES - rowBase);

    int bt = (tid < NBKT) ? btotal[tid] : 0;
    int bincl = scan_incl<512>(bt, tid, wsum);
    if (tid == k) { s_base = bincl - bt; s_end = bincl; }
    hist[tid] = 0;
    curso[tid] = 0;
    __syncthreads();
    int base = s_base;
    int cnt  = s_end - base;

    for (int t = tid; t < cnt; t += 512)
        atomicAdd(&hist[((unsigned)staged[base + t].x) >> 18], 1);
    __syncthreads();
    int h = hist[tid];
    int hincl = scan_incl<512>(h, tid, wsum);
    lstart[tid] = hincl - h;
    __syncthreads();
    for (int t = tid; t < cnt; t += 512) {
        int2 rec = staged[base + t];
        int rl = ((unsigned)rec.x) >> 18;
        int c  = rec.x & 0x3FFFF;
        int off = lstart[rl] + atomicAdd(&curso[rl], 1);
        edges[base + off] = make_int2(c, rec.y);
    }
    if (tid < numRows) {
        counts[rowBase + tid]   = hist[tid];
        startArr[rowBase + tid] = base + lstart[tid];
    }
}

// ---------------------------------------------------------------------------
// Quad-gather SpMM core (fp8 table).
// 64 lanes = 4 groups of 16; group g handles edges 4q+g. Lane li in a group
// reads one uint (4 fp8 dims) -> 16 lanes cover the 64 B row. ONE vmem
// instruction fetches FOUR edges' rows. Bound by random-gather line traffic
// (~1 row-miss per edge) -- at the structural floor; do not grow flights.
// ---------------------------------------------------------------------------
template<int P>
__device__ __forceinline__ void qflight(const int2* __restrict__ edges,
                                        const unsigned* __restrict__ tab,
                                        int s, int q, int g, int li,
                                        float& a0, float& a1, float& a2, float& a3) {
    unsigned u[P];
    float    v[P];
    #pragma unroll
    for (int t = 0; t < P; t++) {
        int2 e = edges[s + 4 * (q + t) + g];   // 16 lanes share addr -> 1 line
        v[t] = __int_as_float(e.y);
        u[t] = tab[(size_t)e.x * 16 + li];     // 16 lanes x 4B = full 64B row
    }
    #pragma unroll
    for (int t = 0; t < P; t++) {
        floatx2 lo = __builtin_amdgcn_cvt_pk_f32_fp8(u[t], false);
        floatx2 hi = __builtin_amdgcn_cvt_pk_f32_fp8(u[t], true);
        a0 = fmaf(v[t], lo.x, a0);
        a1 = fmaf(v[t], lo.y, a1);
        a2 = fmaf(v[t], hi.x, a2);
        a3 = fmaf(v[t], hi.y, a3);
    }
}

__device__ __forceinline__ void spmm_row_q(const int2* __restrict__ edges,
                                           const unsigned* __restrict__ tab,
                                           int s, int n, int g, int li,
                                           float& a0, float& a1, float& a2, float& a3) {
    int nq = n >> 2, rem = n & 3;
    int q = 0;
    for (; q + 8 <= nq; q += 8)
        qflight<8>(edges, tab, s, q, g, li, a0, a1, a2, a3);
    if (nq - q >= 4) { qflight<4>(edges, tab, s, q, g, li, a0, a1, a2, a3); q += 4; }
    if (nq - q >= 2) { qflight<2>(edges, tab, s, q, g, li, a0, a1, a2, a3); q += 2; }
    if (nq - q >= 1) { qflight<1>(edges, tab, s, q, g, li, a0, a1, a2, a3); q += 1; }
    if (rem) {                                  // last 1-3 edges, masked
        int gi = (g < rem) ? g : 0;
        int2 e = edges[s + 4 * nq + gi];
        float v = (g < rem) ? __int_as_float(e.y) : 0.f;
        unsigned u = tab[(size_t)e.x * 16 + li];
        floatx2 lo = __builtin_amdgcn_cvt_pk_f32_fp8(u, false);
        floatx2 hi = __builtin_amdgcn_cvt_pk_f32_fp8(u, true);
        a0 = fmaf(v, lo.x, a0);
        a1 = fmaf(v, lo.y, a1);
        a2 = fmaf(v, hi.x, a2);
        a3 = fmaf(v, hi.y, a3);
    }
}

// ---------------------------------------------------------------------------
// Gather SpMM (fp8): one wave per row, quad-gather layout.
// ---------------------------------------------------------------------------
__global__ __launch_bounds__(256) void k_spmm_csr(const int* __restrict__ startArr,
                                                  const int* __restrict__ counts,
                                                  const int2* __restrict__ edges,
                                                  const unsigned* __restrict__ cur,
                                                  unsigned* __restrict__ nxt) {
    int row  = blockIdx.x * 4 + (threadIdx.x >> 6);
    if (row >= N_NODES) return;
    row = __builtin_amdgcn_readfirstlane(row);
    int lane = threadIdx.x & 63;
    int g  = lane >> 4;
    int li = lane & 15;
    int s = __builtin_amdgcn_readfirstlane(startArr[row]);
    int n = __builtin_amdgcn_readfirstlane(counts[row]);

    float a0 = 0.f, a1 = 0.f, a2 = 0.f, a3 = 0.f;
    spmm_row_q(edges, cur, s, n, g, li, a0, a1, a2, a3);

    // combine the 4 edge-groups (butterfly over lane^16, lane^32)
    a0 += __shfl_xor(a0, 16); a0 += __shfl_xor(a0, 32);
    a1 += __shfl_xor(a1, 16); a1 += __shfl_xor(a1, 32);
    a2 += __shfl_xor(a2, 16); a2 += __shfl_xor(a2, 32);
    a3 += __shfl_xor(a3, 16); a3 += __shfl_xor(a3, 32);
    if (g == 0)
        nxt[(size_t)row * 16 + li] = pk4_fp8(a0, a1, a2, a3);
}

// ---------------------------------------------------------------------------
// Fused layer-3 gathers + layer-2 + layer-1 contributions at selected rows.
// SOLE writer of vsel (pure store; layer-0 is added inside k_mlp).
// ---------------------------------------------------------------------------
__global__ __launch_bounds__(256) void k_spmm_sel(const int* __restrict__ users,
                                                  const int* __restrict__ items,
                                                  const int* __restrict__ startArr,
                                                  const int* __restrict__ counts,
                                                  const int2* __restrict__ edges,
                                                  const unsigned* __restrict__ cur,
                                                  const unsigned* __restrict__ lay1,
                                                  float* __restrict__ vsel) {
    int wave = blockIdx.x * 4 + (threadIdx.x >> 6);
    int lane = threadIdx.x & 63;
    int g  = lane >> 4;
    int li = lane & 15;
    int b, row, off;
    if (wave < BATCH) { b = wave;         row = users[b];             off = 0; }
    else              { b = wave - BATCH; row = NUM_USERS + items[b]; off = 64; }
    row = __builtin_amdgcn_readfirstlane(row);
    int s = __builtin_amdgcn_readfirstlane(startArr[row]);
    int n = __builtin_amdgcn_readfirstlane(counts[row]);

    float a0 = 0.f, a1 = 0.f, a2 = 0.f, a3 = 0.f;
    if (g == 0) {                          // layer-2 + layer-1 contributions
        unsigned u2 = cur [(size_t)row * 16 + li];
        unsigned u1 = lay1[(size_t)row * 16 + li];
        floatx2 lo2 = __builtin_amdgcn_cvt_pk_f32_fp8(u2, false);
        floatx2 hi2 = __builtin_amdgcn_cvt_pk_f32_fp8(u2, true);
        floatx2 lo1 = __builtin_amdgcn_cvt_pk_f32_fp8(u1, false);
        floatx2 hi1 = __builtin_amdgcn_cvt_pk_f32_fp8(u1, true);
        a0 = lo2.x + lo1.x; a1 = lo2.y + lo1.y;
        a2 = hi2.x + hi1.x; a3 = hi2.y + hi1.y;
    }
    spmm_row_q(edges, cur, s, n, g, li, a0, a1, a2, a3);

    a0 += __shfl_xor(a0, 16); a0 += __shfl_xor(a0, 32);
    a1 += __shfl_xor(a1, 16); a1 += __shfl_xor(a1, 32);
    a2 += __shfl_xor(a2, 16); a2 += __shfl_xor(a2, 32);
    a3 += __shfl_xor(a3, 16); a3 += __shfl_xor(a3, 32);
    if (g == 0) {
        float4* p = (float4*)(vsel + (size_t)b * 128 + off) + li;
        *p = make_float4(a0, a1, a2, a3);          // pure store, no RMW
    }
}

// ---------------------------------------------------------------------------
// MLP head v4: 4 threads per batch row (k-split), shfl_xor reduction.
// Fuses the layer-0 embedding gather (v = vsel + emb0).
// ---------------------------------------------------------------------------
__global__ __launch_bounds__(256) void k_mlp(const float* __restrict__ vsel,
                                             const int* __restrict__ users,
                                             const int* __restrict__ items,
                                             const float* __restrict__ ue,
                                             const float* __restrict__ ie,
                                             const float* __restrict__ W0,
                                             const float* __restrict__ b0,
                                             const float* __restrict__ W1,
                                             const float* __restrict__ b1,
                                             const float* __restrict__ Wa,
                                             const float* __restrict__ ba,
                                             float* __restrict__ out) {
    __shared__ float sW0[128 * 64];
    __shared__ float sW1[64 * 32];
    __shared__ float sWa[32];
    __shared__ float sb0[64];
    __shared__ float sb1[32];

    for (int i = threadIdx.x; i < 128 * 64; i += 256) sW0[i] = W0[i];
    for (int i = threadIdx.x; i < 64 * 32;  i += 256) sW1[i] = W1[i];
    if (threadIdx.x < 32) sWa[threadIdx.x] = Wa[threadIdx.x];
    if (threadIdx.x < 64) sb0[threadIdx.x] = b0[threadIdx.x];
    if (threadIdx.x >= 64 && threadIdx.x < 96) sb1[threadIdx.x - 64] = b1[threadIdx.x - 64];
    float sba = ba[0];
    __syncthreads();

    int t = blockIdx.x * 256 + threadIdx.x;
    int b = t >> 2, sub = t & 3;                     // 4 threads per row
    const float4* v4 = (const float4*)(vsel + (size_t)b * 128) + sub * 8;
    const float*  eb = (sub < 2) ? (ue + (size_t)users[b] * 64)
                                 : (ie + (size_t)items[b] * 64);
    const float4* e4 = (const float4*)eb + (sub & 1) * 8;

    float h0[64];
    #pragma unroll
    for (int j = 0; j < 64; j++) h0[j] = 0.f;

    for (int k0 = 0; k0 < 8; k0++) {                 // 8 float4 = 32 of 128 in
        float4 va = v4[k0];
        float4 ea = e4[k0];
        float a0 = (va.x + ea.x) * 0.25f, a1 = (va.y + ea.y) * 0.25f;
        float a2 = (va.z + ea.z) * 0.25f, a3 = (va.w + ea.w) * 0.25f;
        const float* w = &sW0[(sub * 32 + k0 * 4) * 64];
        #pragma unroll
        for (int j = 0; j < 64; j++) {
            h0[j] = fmaf(a0, w[j],       h0[j]);
            h0[j] = fmaf(a1, w[64 + j],  h0[j]);
            h0[j] = fmaf(a2, w[128 + j], h0[j]);
            h0[j] = fmaf(a3, w[192 + j], h0[j]);
        }
    }
    // reduce partials across the 4 subs (quad stays inside the wave)
    #pragma unroll
    for (int j = 0; j < 64; j++) {
        h0[j] += __shfl_xor(h0[j], 1);
        h0[j] += __shfl_xor(h0[j], 2);
        h0[j] = fmaxf(h0[j] + sb0[j], 0.f);
    }

    float h1[32];
    #pragma unroll
    for (int j = 0; j < 32; j++) h1[j] = 0.f;
    for (int k = 0; k < 16; k++) {                   // k-split of 64 by 4
        float a = h0[sub * 16 + k];
        const float* w = &sW1[(sub * 16 + k) * 32];
        #pragma unroll
        for (int j = 0; j < 32; j++)
            h1[j] = fmaf(a, w[j], h1[j]);
    }
    #pragma unroll
    for (int j = 0; j < 32; j++) {
        h1[j] += __shfl_xor(h1[j], 1);
        h1[j] += __shfl_xor(h1[j], 2);
    }

    float logit = sba;
    #pragma unroll
    for (int j = 0; j < 32; j++)
        logit = fmaf(fmaxf(h1[j] + sb1[j], 0.f), sWa[j], logit);

    if (sub == 0) out[b] = 1.0f / (1.0f + expf(-logit));
}

// ---------------------------------------------------------------------------
extern "C" void kernel_launch(void* const* d_in, const int* in_sizes, int n_in,
                              void* d_out, int out_size, void* d_ws, size_t ws_size,
                              hipStream_t stream) {
    const int*   users = (const int*)  d_in[0];
    const int*   items = (const int*)  d_in[1];
    const int*   rows  = (const int*)  d_in[2];
    const int*   cols  = (const int*)  d_in[3];
    const float* vals  = (const float*)d_in[4];
    const float* ue    = (const float*)d_in[5];
    const float* ie    = (const float*)d_in[6];
    const float* W0    = (const float*)d_in[7];
    const float* b0    = (const float*)d_in[8];
    const float* W1    = (const float*)d_in[9];
    const float* b1    = (const float*)d_in[10];
    const float* Wa    = (const float*)d_in[11];
    const float* ba    = (const float*)d_in[12];
    float* out = (float*)d_out;

    char* ws = (char*)d_ws;
    unsigned* tabA8 = (unsigned*)ws;  ws += (size_t)N_NODES * 64;                // 9.6 MB
    unsigned* tabB8 = (unsigned*)ws;  ws += (size_t)N_NODES * 64;                // 9.6 MB
    float* vsel = (float*)ws;         ws += (size_t)BATCH * 128 * 4;             // 8.39 MB
    int2*  edges  = (int2*)ws;        ws += (size_t)N_EDGES * 8;                 // 19.2 MB
    int2*  staged = (int2*)ws;        ws += (size_t)N_EDGES * 8;                 // 19.2 MB
    int* counts   = (int*)ws;         ws += N_NODES * 4;
    int* startArr = (int*)ws;         ws += N_NODES * 4;
    int* cmat     = (int*)ws;         ws += (size_t)NBKT * NBLK * 4;             // 686 KB
    int* bcnt     = (int*)ws;         ws += (size_t)NBKT * NBLK * 4;             // 686 KB
    int* btotal   = (int*)ws;         ws += NBKT * 4;

    // fp8 table + p1a histogram (fused, one dispatch)
    k_prep<<<NBLK + CONCAT_BLKS, 256, 0, stream>>>(
        (const float4*)ue, (const float4*)ie, tabA8, rows, cmat);

    // ---- CSR build: zero global atomics, no bscan dispatch ----
    k_p1b<<<NBKT, 1024, 0, stream>>>(cmat, bcnt, btotal);
    k_p1c<<<NBLK, 512, 0, stream>>>(rows, cols, vals, cmat, bcnt, btotal, staged);
    k_p2<<<NBKT, 512, 0, stream>>>(btotal, staged, edges, counts, startArr);

    // layer 1: A -> B (writes every row; no memset needed)
    k_spmm_csr<<<(N_NODES + 3) / 4, 256, 0, stream>>>(startArr, counts, edges, tabA8, tabB8);

    // layer 2: B -> A  (tabB8 stays intact for the fused sel below)
    k_spmm_csr<<<(N_NODES + 3) / 4, 256, 0, stream>>>(startArr, counts, edges, tabB8, tabA8);

    // layer 3 gathers + layer-2 + layer-1 adds at selected rows (fused);
    // sole writer of vsel
    k_spmm_sel<<<(2 * BATCH) / 4, 256, 0, stream>>>(users, items, startArr,
                                                    counts, edges, tabA8, tabB8, vsel);

    // MLP head: 4 threads per row, layer-0 gather fused
    k_mlp<<<(BATCH * 4) / 256, 256, 0, stream>>>(vsel, users, items, ue, ie,
                                                 W0, b0, W1, b1, Wa, ba, out);
}

// Round 6
// 319.243 us; speedup vs baseline: 1.1986x; 1.0367x over previous
//
#include <hip/hip_runtime.h>
#include <math.h>

#define NUM_USERS 100000
#define NUM_ITEMS 50000
#define N_NODES   150000   // NUM_USERS + NUM_ITEMS
#define LATENT    64
#define N_EDGES   2400000
#define BATCH     16384

// Multisplit fill: 4096-edge chunks, 512-row buckets
#define CHUNK 4096
#define NBLK  ((N_EDGES + CHUNK - 1) / CHUNK)   // 586
#define NBKT  ((N_NODES + 511) / 512)           // 293

typedef __attribute__((ext_vector_type(2))) float floatx2;

// fp8 e4m3 pack/unpack via gfx950 HW converters (encode+decode self-consistent)
__device__ __forceinline__ unsigned pk4_fp8(float a, float b, float c, float d) {
    int u = __builtin_amdgcn_cvt_pk_fp8_f32(a, b, 0, false);
    u     = __builtin_amdgcn_cvt_pk_fp8_f32(c, d, u, true);
    return (unsigned)u;
}

// ---------------------------------------------------------------------------
// Inclusive wave-hierarchical scan across NT threads (3 barriers, not 18).
// wsums = LDS scratch of NT/64 ints. Entry barrier protects prior wsums use.
// ---------------------------------------------------------------------------
template<int NT>
__device__ __forceinline__ int scan_incl(int v, int tid, int* wsums) {
    int lane = tid & 63, wid = tid >> 6;
    __syncthreads();
    int x = v;
    #pragma unroll
    for (int d = 1; d < 64; d <<= 1) {
        int y = __shfl_up(x, d);
        if (lane >= d) x += y;
    }
    if (lane == 63) wsums[wid] = x;
    __syncthreads();
    constexpr int NW = NT / 64;
    if (wid == 0) {
        int w = (lane < NW) ? wsums[lane] : 0;
        #pragma unroll
        for (int d = 1; d < NW; d <<= 1) {
            int y = __shfl_up(w, d);
            if (lane >= d) w += y;
        }
        if (lane < NW) wsums[lane] = w;
    }
    __syncthreads();
    return x + (wid ? wsums[wid - 1] : 0);
}

// ---------------------------------------------------------------------------
// Fused prep: [blocks 0..NBLK-1]  p1a bucket histogram -> cmat[bucket][block]
//             [blocks NBLK.. ]    tab = fp8(concat(user_emb, item_emb))
// ---------------------------------------------------------------------------
#define CONCAT_BLKS ((N_NODES * 16) / 256)      // 9375
__global__ __launch_bounds__(256) void k_prep(const float4* __restrict__ ue4,
                                              const float4* __restrict__ ie4,
                                              unsigned* __restrict__ tab,
                                              const int* __restrict__ rows,
                                              int* __restrict__ cmat) {
    if (blockIdx.x < NBLK) {
        __shared__ int hist[NBKT];
        for (int i = threadIdx.x; i < NBKT; i += 256) hist[i] = 0;
        __syncthreads();
        int e0 = blockIdx.x * CHUNK;
        int cnt = min(CHUNK, N_EDGES - e0);          // 4096 or 3840: %4 == 0
        const int4* r4 = (const int4*)(rows + e0);
        for (int t = threadIdx.x; t < (cnt >> 2); t += 256) {
            int4 r = r4[t];
            atomicAdd(&hist[r.x >> 9], 1);
            atomicAdd(&hist[r.y >> 9], 1);
            atomicAdd(&hist[r.z >> 9], 1);
            atomicAdd(&hist[r.w >> 9], 1);
        }
        __syncthreads();
        for (int i = threadIdx.x; i < NBKT; i += 256)
            cmat[i * NBLK + blockIdx.x] = hist[i];
    } else {
        int i = (blockIdx.x - NBLK) * 256 + threadIdx.x;
        const int nU4 = NUM_USERS * 16;
        float4 v = (i < nU4) ? ue4[i] : ie4[i - nU4];
        tab[i] = pk4_fp8(v.x, v.y, v.z, v.w);
    }
}

// ---------------------------------------------------------------------------
// Multisplit p1b: per-bucket exclusive scan over blocks (hierarchical wave
// scan). Saves raw counts to bcnt for p1c; emits bucket total.
// ---------------------------------------------------------------------------
__global__ __launch_bounds__(1024) void k_p1b(int* __restrict__ cmat,
                                              int* __restrict__ bcnt,
                                              int* __restrict__ btotal) {
    __shared__ int wsum[16];
    int k = blockIdx.x;
    int tid = threadIdx.x;
    int lane = tid & 63, wid = tid >> 6;
    int v = (tid < NBLK) ? cmat[k * NBLK + tid] : 0;
    if (tid < NBLK) bcnt[k * NBLK + tid] = v;        // raw counts for p1c
    int x = v;
    #pragma unroll
    for (int d = 1; d < 64; d <<= 1) {
        int y = __shfl_up(x, d);
        if (lane >= d) x += y;
    }
    if (lane == 63) wsum[wid] = x;
    __syncthreads();
    if (wid == 0 && lane < 16) {
        int w = wsum[lane];
        #pragma unroll
        for (int d = 1; d < 16; d <<= 1) {
            int y = __shfl_up(w, d);
            if (lane >= d) w += y;
        }
        wsum[lane] = w;
    }
    __syncthreads();
    int incl = x + (wid ? wsum[wid - 1] : 0);
    if (tid < NBLK) cmat[k * NBLK + tid] = incl - v; // exclusive
    if (tid == 1023) btotal[k] = incl;               // padding adds 0
}

// ---------------------------------------------------------------------------
// Multisplit p1c (512 thr): bin records in LDS using p1b's saved counts,
// flush bucket-contiguous runs at exact offsets. Bucket bases computed
// in-LDS from btotal (no bscan kernel). Zero global atomics.
// Record: x = col(18b) | rowLo(9b)<<18 ; y = fp32 val bits.
// ---------------------------------------------------------------------------
__global__ __launch_bounds__(512) void k_p1c(const int* __restrict__ rows,
                                             const int* __restrict__ cols,
                                             const float* __restrict__ vals,
                                             const int* __restrict__ offs,
                                             const int* __restrict__ bcnt,
                                             const int* __restrict__ btotal,
                                             int2* __restrict__ staged) {
    __shared__ int hist[NBKT];
    __shared__ int lstart[NBKT];
    __shared__ int cursor[NBKT];
    __shared__ int soffs[NBKT];
    __shared__ int wsum[8];
    __shared__ int2 st[CHUNK];
    __shared__ unsigned short bkt16[CHUNK];

    int tid = threadIdx.x;
    int e0 = blockIdx.x * CHUNK;
    int cnt = min(CHUNK, N_EDGES - e0);              // %4 == 0 always

    // bucket bases from btotal (global prefix), chunk-local hist from bcnt
    int bt = (tid < NBKT) ? btotal[tid] : 0;
    int bincl = scan_incl<512>(bt, tid, wsum);       // inclusive
    int h = 0;
    if (tid < NBKT) {
        h = bcnt[tid * NBLK + blockIdx.x];
        hist[tid] = h;
        cursor[tid] = 0;
        soffs[tid] = offs[tid * NBLK + blockIdx.x] + (bincl - bt);  // + bbase
    }
    // chunk-local exclusive starts
    int hincl = scan_incl<512>(h, tid, wsum);
    if (tid < NBKT) lstart[tid] = hincl - h;
    __syncthreads();

    // bin into LDS staging (vectorized 4-edge input stream)
    const int4*   r4 = (const int4*)  (rows + e0);
    const int4*   c4 = (const int4*)  (cols + e0);
    const float4* v4 = (const float4*)(vals + e0);
    for (int t = tid; t < (cnt >> 2); t += 512) {
        int4 r = r4[t];
        int4 c = c4[t];
        float4 v = v4[t];
        int b0 = r.x >> 9, b1 = r.y >> 9, b2 = r.z >> 9, b3 = r.w >> 9;
        int p0 = lstart[b0] + atomicAdd(&cursor[b0], 1);
        st[p0] = make_int2(c.x | ((r.x & 511) << 18), __float_as_int(v.x));
        bkt16[p0] = (unsigned short)b0;
        int p1 = lstart[b1] + atomicAdd(&cursor[b1], 1);
        st[p1] = make_int2(c.y | ((r.y & 511) << 18), __float_as_int(v.y));
        bkt16[p1] = (unsigned short)b1;
        int p2 = lstart[b2] + atomicAdd(&cursor[b2], 1);
        st[p2] = make_int2(c.z | ((r.z & 511) << 18), __float_as_int(v.z));
        bkt16[p2] = (unsigned short)b2;
        int p3 = lstart[b3] + atomicAdd(&cursor[b3], 1);
        st[p3] = make_int2(c.w | ((r.w & 511) << 18), __float_as_int(v.w));
        bkt16[p3] = (unsigned short)b3;
    }
    __syncthreads();
    // flush: consecutive threads in a bucket write consecutive global addrs
    for (int t = tid; t < cnt; t += 512) {
        int b = bkt16[t];
        staged[soffs[b] + (t - lstart[b])] = st[t];
    }
}

// ---------------------------------------------------------------------------
// Multisplit p2 (512 thr): one block per bucket; bucket base from in-LDS
// btotal scan; row histogram; wave-scan -> local row starts; place records;
// emit counts/startArr.
// ---------------------------------------------------------------------------
__global__ __launch_bounds__(512) void k_p2(const int* __restrict__ btotal,
                                            const int2* __restrict__ staged,
                                            int2* __restrict__ edges,
                                            int* __restrict__ counts,
                                            int* __restrict__ startArr) {
    __shared__ int hist[512];
    __shared__ int lstart[512];
    __shared__ int curso[512];
    __shared__ int wsum[8];
    __shared__ int s_base, s_end;
    int k = blockIdx.x;
    int tid = threadIdx.x;
    int rowBase = k << 9;
    int numRows = min(512, N_NODES - rowBase);

    int bt = (tid < NBKT) ? btotal[tid] : 0;
    int bincl = scan_incl<512>(bt, tid, wsum);
    if (tid == k) { s_base = bincl - bt; s_end = bincl; }
    hist[tid] = 0;
    curso[tid] = 0;
    __syncthreads();
    int base = s_base;
    int cnt  = s_end - base;

    for (int t = tid; t < cnt; t += 512)
        atomicAdd(&hist[((unsigned)staged[base + t].x) >> 18], 1);
    __syncthreads();
    int h = hist[tid];
    int hincl = scan_incl<512>(h, tid, wsum);
    lstart[tid] = hincl - h;
    __syncthreads();
    for (int t = tid; t < cnt; t += 512) {
        int2 rec = staged[base + t];
        int rl = ((unsigned)rec.x) >> 18;
        int c  = rec.x & 0x3FFFF;
        int off = lstart[rl] + atomicAdd(&curso[rl], 1);
        edges[base + off] = make_int2(c, rec.y);
    }
    if (tid < numRows) {
        counts[rowBase + tid]   = hist[tid];
        startArr[rowBase + tid] = base + lstart[tid];
    }
}

// ---------------------------------------------------------------------------
// Quad-gather SpMM core (fp8 table).
// 64 lanes = 4 groups of 16; group g handles edges 4q+g. Lane li in a group
// reads one uint (4 fp8 dims) -> 16 lanes cover the 64 B row. ONE vmem
// instruction fetches FOUR edges' rows. Bound by random-gather line traffic
// (~1 row-miss per edge) -- at the structural floor; do not grow flights.
// ---------------------------------------------------------------------------
template<int P>
__device__ __forceinline__ void qflight(const int2* __restrict__ edges,
                                        const unsigned* __restrict__ tab,
                                        int s, int q, int g, int li,
                                        float& a0, float& a1, float& a2, float& a3) {
    unsigned u[P];
    float    v[P];
    #pragma unroll
    for (int t = 0; t < P; t++) {
        int2 e = edges[s + 4 * (q + t) + g];   // 16 lanes share addr -> 1 line
        v[t] = __int_as_float(e.y);
        u[t] = tab[(size_t)e.x * 16 + li];     // 16 lanes x 4B = full 64B row
    }
    #pragma unroll
    for (int t = 0; t < P; t++) {
        floatx2 lo = __builtin_amdgcn_cvt_pk_f32_fp8(u[t], false);
        floatx2 hi = __builtin_amdgcn_cvt_pk_f32_fp8(u[t], true);
        a0 = fmaf(v[t], lo.x, a0);
        a1 = fmaf(v[t], lo.y, a1);
        a2 = fmaf(v[t], hi.x, a2);
        a3 = fmaf(v[t], hi.y, a3);
    }
}

__device__ __forceinline__ void spmm_row_q(const int2* __restrict__ edges,
                                           const unsigned* __restrict__ tab,
                                           int s, int n, int g, int li,
                                           float& a0, float& a1, float& a2, float& a3) {
    int nq = n >> 2, rem = n & 3;
    int q = 0;
    for (; q + 8 <= nq; q += 8)
        qflight<8>(edges, tab, s, q, g, li, a0, a1, a2, a3);
    if (nq - q >= 4) { qflight<4>(edges, tab, s, q, g, li, a0, a1, a2, a3); q += 4; }
    if (nq - q >= 2) { qflight<2>(edges, tab, s, q, g, li, a0, a1, a2, a3); q += 2; }
    if (nq - q >= 1) { qflight<1>(edges, tab, s, q, g, li, a0, a1, a2, a3); q += 1; }
    if (rem) {                                  // last 1-3 edges, masked
        int gi = (g < rem) ? g : 0;
        int2 e = edges[s + 4 * nq + gi];
        float v = (g < rem) ? __int_as_float(e.y) : 0.f;
        unsigned u = tab[(size_t)e.x * 16 + li];
        floatx2 lo = __builtin_amdgcn_cvt_pk_f32_fp8(u, false);
        floatx2 hi = __builtin_amdgcn_cvt_pk_f32_fp8(u, true);
        a0 = fmaf(v, lo.x, a0);
        a1 = fmaf(v, lo.y, a1);
        a2 = fmaf(v, hi.x, a2);
        a3 = fmaf(v, hi.y, a3);
    }
}

// ---------------------------------------------------------------------------
// Gather SpMM (fp8): one wave per row, quad-gather layout.
// ---------------------------------------------------------------------------
__global__ __launch_bounds__(256) void k_spmm_csr(const int* __restrict__ startArr,
                                                  const int* __restrict__ counts,
                                                  const int2* __restrict__ edges,
                                                  const unsigned* __restrict__ cur,
                                                  unsigned* __restrict__ nxt) {
    int row  = blockIdx.x * 4 + (threadIdx.x >> 6);
    if (row >= N_NODES) return;
    row = __builtin_amdgcn_readfirstlane(row);
    int lane = threadIdx.x & 63;
    int g  = lane >> 4;
    int li = lane & 15;
    int s = __builtin_amdgcn_readfirstlane(startArr[row]);
    int n = __builtin_amdgcn_readfirstlane(counts[row]);

    float a0 = 0.f, a1 = 0.f, a2 = 0.f, a3 = 0.f;
    spmm_row_q(edges, cur, s, n, g, li, a0, a1, a2, a3);

    // combine the 4 edge-groups (butterfly over lane^16, lane^32)
    a0 += __shfl_xor(a0, 16); a0 += __shfl_xor(a0, 32);
    a1 += __shfl_xor(a1, 16); a1 += __shfl_xor(a1, 32);
    a2 += __shfl_xor(a2, 16); a2 += __shfl_xor(a2, 32);
    a3 += __shfl_xor(a3, 16); a3 += __shfl_xor(a3, 32);
    if (g == 0)
        nxt[(size_t)row * 16 + li] = pk4_fp8(a0, a1, a2, a3);
}

// ---------------------------------------------------------------------------
// Fused layer-3 gathers + layer-2 + layer-1 contributions at selected rows.
// SOLE writer of vsel (pure store; layer-0 is added inside k_mlp).
// ---------------------------------------------------------------------------
__global__ __launch_bounds__(256) void k_spmm_sel(const int* __restrict__ users,
                                                  const int* __restrict__ items,
                                                  const int* __restrict__ startArr,
                                                  const int* __restrict__ counts,
                                                  const int2* __restrict__ edges,
                                                  const unsigned* __restrict__ cur,
                                                  const unsigned* __restrict__ lay1,
                                                  float* __restrict__ vsel) {
    int wave = blockIdx.x * 4 + (threadIdx.x >> 6);
    int lane = threadIdx.x & 63;
    int g  = lane >> 4;
    int li = lane & 15;
    int b, row, off;
    if (wave < BATCH) { b = wave;         row = users[b];             off = 0; }
    else              { b = wave - BATCH; row = NUM_USERS + items[b]; off = 64; }
    row = __builtin_amdgcn_readfirstlane(row);
    int s = __builtin_amdgcn_readfirstlane(startArr[row]);
    int n = __builtin_amdgcn_readfirstlane(counts[row]);

    float a0 = 0.f, a1 = 0.f, a2 = 0.f, a3 = 0.f;
    if (g == 0) {                          // layer-2 + layer-1 contributions
        unsigned u2 = cur [(size_t)row * 16 + li];
        unsigned u1 = lay1[(size_t)row * 16 + li];
        floatx2 lo2 = __builtin_amdgcn_cvt_pk_f32_fp8(u2, false);
        floatx2 hi2 = __builtin_amdgcn_cvt_pk_f32_fp8(u2, true);
        floatx2 lo1 = __builtin_amdgcn_cvt_pk_f32_fp8(u1, false);
        floatx2 hi1 = __builtin_amdgcn_cvt_pk_f32_fp8(u1, true);
        a0 = lo2.x + lo1.x; a1 = lo2.y + lo1.y;
        a2 = hi2.x + hi1.x; a3 = hi2.y + hi1.y;
    }
    spmm_row_q(edges, cur, s, n, g, li, a0, a1, a2, a3);

    a0 += __shfl_xor(a0, 16); a0 += __shfl_xor(a0, 32);
    a1 += __shfl_xor(a1, 16); a1 += __shfl_xor(a1, 32);
    a2 += __shfl_xor(a2, 16); a2 += __shfl_xor(a2, 32);
    a3 += __shfl_xor(a3, 16); a3 += __shfl_xor(a3, 32);
    if (g == 0) {
        float4* p = (float4*)(vsel + (size_t)b * 128 + off) + li;
        *p = make_float4(a0, a1, a2, a3);          // pure store, no RMW
    }
}

// ---------------------------------------------------------------------------
// MLP head v5: thread = (row, output-quarter). NO runtime-indexed arrays
// (v4's h0[sub*16+k] spilled 64 floats/thread to scratch -> 36 MB writes,
// 65 us). Each thread owns 16 h0 neurons over all 128 inputs; h1 k-split
// by sub with shfl_xor reduce. W1 panels skewed by 8 floats so the 4 subs
// hit banks {0,8,16,24}; W0 quarter-columns are 64 B apart = free 2-way.
// All weight reads are float4 (b128). VGPR ~96, no spill.
// ---------------------------------------------------------------------------
__global__ __launch_bounds__(256) void k_mlp(const float* __restrict__ vsel,
                                             const int* __restrict__ users,
                                             const int* __restrict__ items,
                                             const float* __restrict__ ue,
                                             const float* __restrict__ ie,
                                             const float* __restrict__ W0,
                                             const float* __restrict__ b0,
                                             const float* __restrict__ W1,
                                             const float* __restrict__ b1,
                                             const float* __restrict__ Wa,
                                             const float* __restrict__ ba,
                                             float* __restrict__ out) {
    __shared__ float sW0[128 * 64];          // row-major, as given
    __shared__ float sW1[4 * 520];           // 4 panels of 16 rows, +8 skew
    __shared__ float sWa[32];
    __shared__ float sb0[64];
    __shared__ float sb1[32];

    for (int i = threadIdx.x; i < 128 * 64; i += 256) sW0[i] = W0[i];
    for (int i = threadIdx.x; i < 64 * 32; i += 256) {
        int k = i >> 5, j = i & 31;
        sW1[(k >> 4) * 520 + (k & 15) * 32 + j] = W1[i];
    }
    if (threadIdx.x < 32) sWa[threadIdx.x] = Wa[threadIdx.x];
    if (threadIdx.x < 64) sb0[threadIdx.x] = b0[threadIdx.x];
    if (threadIdx.x >= 64 && threadIdx.x < 96) sb1[threadIdx.x - 64] = b1[threadIdx.x - 64];
    float sba = ba[0];
    __syncthreads();

    int t = blockIdx.x * 256 + threadIdx.x;
    int b = t >> 2, sub = t & 3;                     // 4 threads per row
    const float4* v4  = (const float4*)(vsel + (size_t)b * 128);
    const float4* ue4 = (const float4*)(ue + (size_t)users[b] * 64);
    const float4* ie4 = (const float4*)(ie + (size_t)items[b] * 64);

    // h0s[j] = thread's 16 neurons (cols sub*16 .. +15), bias-initialized
    float h0s[16];
    {
        const float4* bb = (const float4*)&sb0[sub * 16];
        #pragma unroll
        for (int q = 0; q < 4; q++) {
            float4 bv = bb[q];
            h0s[q * 4 + 0] = bv.x; h0s[q * 4 + 1] = bv.y;
            h0s[q * 4 + 2] = bv.z; h0s[q * 4 + 3] = bv.w;
        }
    }

    #pragma unroll
    for (int k0 = 0; k0 < 32; k0++) {                // 4 inputs per iter
        float4 va = v4[k0];
        float4 ea = (k0 < 16) ? ue4[k0] : ie4[k0 - 16];
        float a[4] = { (va.x + ea.x) * 0.25f, (va.y + ea.y) * 0.25f,
                       (va.z + ea.z) * 0.25f, (va.w + ea.w) * 0.25f };
        #pragma unroll
        for (int r = 0; r < 4; r++) {
            const float4* w4 = (const float4*)&sW0[(k0 * 4 + r) * 64 + sub * 16];
            float ar = a[r];
            #pragma unroll
            for (int q = 0; q < 4; q++) {
                float4 wv = w4[q];
                h0s[q * 4 + 0] = fmaf(ar, wv.x, h0s[q * 4 + 0]);
                h0s[q * 4 + 1] = fmaf(ar, wv.y, h0s[q * 4 + 1]);
                h0s[q * 4 + 2] = fmaf(ar, wv.z, h0s[q * 4 + 2]);
                h0s[q * 4 + 3] = fmaf(ar, wv.w, h0s[q * 4 + 3]);
            }
        }
    }
    #pragma unroll
    for (int j = 0; j < 16; j++) h0s[j] = fmaxf(h0s[j], 0.f);

    // h1 partials from this thread's 16 h0 rows (W1 rows sub*16..+15)
    float h1p[32];
    #pragma unroll
    for (int j = 0; j < 32; j++) h1p[j] = 0.f;
    #pragma unroll
    for (int kk = 0; kk < 16; kk++) {
        float a = h0s[kk];
        const float4* w4 = (const float4*)&sW1[sub * 520 + kk * 32];
        #pragma unroll
        for (int q = 0; q < 8; q++) {
            float4 wv = w4[q];
            h1p[q * 4 + 0] = fmaf(a, wv.x, h1p[q * 4 + 0]);
            h1p[q * 4 + 1] = fmaf(a, wv.y, h1p[q * 4 + 1]);
            h1p[q * 4 + 2] = fmaf(a, wv.z, h1p[q * 4 + 2]);
            h1p[q * 4 + 3] = fmaf(a, wv.w, h1p[q * 4 + 3]);
        }
    }
    // reduce partials across the 4 subs (quad stays inside the wave)
    #pragma unroll
    for (int j = 0; j < 32; j++) {
        h1p[j] += __shfl_xor(h1p[j], 1);
        h1p[j] += __shfl_xor(h1p[j], 2);
    }

    float logit = sba;
    #pragma unroll
    for (int j = 0; j < 32; j++)
        logit = fmaf(fmaxf(h1p[j] + sb1[j], 0.f), sWa[j], logit);

    if (sub == 0) out[b] = 1.0f / (1.0f + expf(-logit));
}

// ---------------------------------------------------------------------------
extern "C" void kernel_launch(void* const* d_in, const int* in_sizes, int n_in,
                              void* d_out, int out_size, void* d_ws, size_t ws_size,
                              hipStream_t stream) {
    const int*   users = (const int*)  d_in[0];
    const int*   items = (const int*)  d_in[1];
    const int*   rows  = (const int*)  d_in[2];
    const int*   cols  = (const int*)  d_in[3];
    const float* vals  = (const float*)d_in[4];
    const float* ue    = (const float*)d_in[5];
    const float* ie    = (const float*)d_in[6];
    const float* W0    = (const float*)d_in[7];
    const float* b0    = (const float*)d_in[8];
    const float* W1    = (const float*)d_in[9];
    const float* b1    = (const float*)d_in[10];
    const float* Wa    = (const float*)d_in[11];
    const float* ba    = (const float*)d_in[12];
    float* out = (float*)d_out;

    char* ws = (char*)d_ws;
    unsigned* tabA8 = (unsigned*)ws;  ws += (size_t)N_NODES * 64;                // 9.6 MB
    unsigned* tabB8 = (unsigned*)ws;  ws += (size_t)N_NODES * 64;                // 9.6 MB
    float* vsel = (float*)ws;         ws += (size_t)BATCH * 128 * 4;             // 8.39 MB
    int2*  edges  = (int2*)ws;        ws += (size_t)N_EDGES * 8;                 // 19.2 MB
    int2*  staged = (int2*)ws;        ws += (size_t)N_EDGES * 8;                 // 19.2 MB
    int* counts   = (int*)ws;         ws += N_NODES * 4;
    int* startArr = (int*)ws;         ws += N_NODES * 4;
    int* cmat     = (int*)ws;         ws += (size_t)NBKT * NBLK * 4;             // 686 KB
    int* bcnt     = (int*)ws;         ws += (size_t)NBKT * NBLK * 4;             // 686 KB
    int* btotal   = (int*)ws;         ws += NBKT * 4;

    // fp8 table + p1a histogram (fused, one dispatch)
    k_prep<<<NBLK + CONCAT_BLKS, 256, 0, stream>>>(
        (const float4*)ue, (const float4*)ie, tabA8, rows, cmat);

    // ---- CSR build: zero global atomics, no bscan dispatch ----
    k_p1b<<<NBKT, 1024, 0, stream>>>(cmat, bcnt, btotal);
    k_p1c<<<NBLK, 512, 0, stream>>>(rows, cols, vals, cmat, bcnt, btotal, staged);
    k_p2<<<NBKT, 512, 0, stream>>>(btotal, staged, edges, counts, startArr);

    // layer 1: A -> B (writes every row; no memset needed)
    k_spmm_csr<<<(N_NODES + 3) / 4, 256, 0, stream>>>(startArr, counts, edges, tabA8, tabB8);

    // layer 2: B -> A  (tabB8 stays intact for the fused sel below)
    k_spmm_csr<<<(N_NODES + 3) / 4, 256, 0, stream>>>(startArr, counts, edges, tabB8, tabA8);

    // layer 3 gathers + layer-2 + layer-1 adds at selected rows (fused);
    // sole writer of vsel
    k_spmm_sel<<<(2 * BATCH) / 4, 256, 0, stream>>>(users, items, startArr,
                                                    counts, edges, tabA8, tabB8, vsel);

    // MLP head: 4 threads per row, layer-0 gather fused, no scratch
    k_mlp<<<(BATCH * 4) / 256, 256, 0, stream>>>(vsel, users, items, ue, ie,
                                                 W0, b0, W1, b1, Wa, ba, out);
}